// Round 2
// baseline (373.904 us; speedup 1.0000x reference)
//
#include <hip/hip_runtime.h>
#include <hip/hip_bf16.h>
#include <math.h>

// Problem constants (fixed by reference)
#define BATCH 2
#define SEQ   1024
#define DM    1024   // D_MODEL
#define MMEM  128    // memory slots
#define MEMD  512    // MEM_DIM
#define RELH  512    // REL_HID

// ---------------------------------------------------------------------------
// Generic fp32 tiled GEMM: C[M,N] = A[M,K] @ W[K,N] (+ bias[N])
// 64x64 tile, BK=16, 256 threads, 4x4 micro-tile per thread.
// Grid: (N/64, M/64). All dims divisible (M in {2048,256}, N in {1024,512},
// K in {1024,512}).
// ---------------------------------------------------------------------------
__global__ __launch_bounds__(256) void gemm_f32(
    const float* __restrict__ A, const float* __restrict__ W,
    const float* __restrict__ bias, float* __restrict__ C,
    int N, int K)
{
    __shared__ float As[16][68];   // A tile transposed: As[k][m], stride 68 (272B, 16B-aligned)
    __shared__ float Bs[16][64];   // B tile natural:    Bs[k][n]

    const int tid = threadIdx.x;
    const int tx = tid & 15;       // 0..15  -> 4 cols each
    const int ty = tid >> 4;       // 0..15  -> 4 rows each
    const size_t row0 = blockIdx.y * 64;
    const size_t col0 = blockIdx.x * 64;

    const int arow = tid >> 2;          // 0..63
    const int akq  = (tid & 3) * 4;     // 0,4,8,12
    const int bkr  = tid >> 4;          // 0..15
    const int bnq  = (tid & 15) * 4;    // 0..60

    float acc[4][4];
    #pragma unroll
    for (int i = 0; i < 4; ++i)
        #pragma unroll
        for (int j = 0; j < 4; ++j) acc[i][j] = 0.f;

    for (int k0 = 0; k0 < K; k0 += 16) {
        __syncthreads();
        // stage A tile (64 rows x 16 k), transpose into As[k][m]
        {
            float4 av = *(const float4*)(A + (row0 + arow) * (size_t)K + k0 + akq);
            As[akq + 0][arow] = av.x;
            As[akq + 1][arow] = av.y;
            As[akq + 2][arow] = av.z;
            As[akq + 3][arow] = av.w;
        }
        // stage B tile (16 k x 64 n)
        {
            *(float4*)(&Bs[bkr][bnq]) =
                *(const float4*)(W + (size_t)(k0 + bkr) * N + col0 + bnq);
        }
        __syncthreads();

        #pragma unroll
        for (int kk = 0; kk < 16; ++kk) {
            float4 a4 = *(const float4*)(&As[kk][ty * 4]);
            float4 b4 = *(const float4*)(&Bs[kk][tx * 4]);
            float a[4] = {a4.x, a4.y, a4.z, a4.w};
            float b[4] = {b4.x, b4.y, b4.z, b4.w};
            #pragma unroll
            for (int i = 0; i < 4; ++i)
                #pragma unroll
                for (int j = 0; j < 4; ++j)
                    acc[i][j] = fmaf(a[i], b[j], acc[i][j]);
        }
    }

    float4 bb = make_float4(0.f, 0.f, 0.f, 0.f);
    if (bias) bb = *(const float4*)(bias + col0 + tx * 4);
    #pragma unroll
    for (int i = 0; i < 4; ++i) {
        float4 c4;
        c4.x = acc[i][0] + bb.x;
        c4.y = acc[i][1] + bb.y;
        c4.z = acc[i][2] + bb.z;
        c4.w = acc[i][3] + bb.w;
        *(float4*)(C + (row0 + ty * 4 + i) * (size_t)N + col0 + tx * 4) = c4;
    }
}

// ---------------------------------------------------------------------------
// Fused relevance -> scores -> softmax -> PV.
// One block = 8 consecutive s-rows of one batch. 256 threads. Grid = 256.
// LDS (55.7 KB): rel[8][128] persistent + phase-scratch (union).
// All hot LDS reads are broadcast or <=2-way bank aliased (free).
// ---------------------------------------------------------------------------
#define TR 8
__global__ __launch_bounds__(256) void fused_attn(
    const float* __restrict__ q_part,   // (B*S, 512)
    const float* __restrict__ m_part,   // (B*M, 512)
    const float* __restrict__ queries,  // (B*S, 1024)
    const float* __restrict__ keys,     // (B*M, 1024)
    const float* __restrict__ values,   // (B*M, 1024)
    const float* __restrict__ W2,       // (512)
    const float* __restrict__ b1,       // (512)
    const float* __restrict__ b2,       // (1)
    float* __restrict__ attn_out,       // (B*S, 1024)
    float* __restrict__ attn_w)         // (B*S, 128)
{
    __shared__ __align__(16) float sm[13920];
    float* rel = sm;               // [8][128] persistent
    float* scratch = sm + 1024;

    const int tid = threadIdx.x;
    const int bidx = blockIdx.x;             // 0..255
    const int b = bidx >> 7;                 // / (SEQ/TR)
    const int s0 = (bidx & 127) * TR;
    const int rowbase = b * SEQ + s0;        // row in (B*S)
    const int mbase = b * MMEM;              // row in (B*M)

    // ---------------- Phase R: relevance ----------------
    {
        float* qb  = scratch;                 // [8][516]
        float* mp  = qb + 8 * 516;            // [16][516]
        float* w2s = mp + 16 * 516;           // [512]

        // stage qb = q_part rows + b1
        {
            const int r = tid >> 5, c = tid & 31;
            #pragma unroll
            for (int k = 0; k < 4; ++k) {
                int h = (c + k * 32) * 4;
                float4 v  = *(const float4*)(q_part + (size_t)(rowbase + r) * RELH + h);
                float4 bv = *(const float4*)(b1 + h);
                float4 o;
                o.x = v.x + bv.x; o.y = v.y + bv.y; o.z = v.z + bv.z; o.w = v.w + bv.w;
                *(float4*)(qb + r * 516 + h) = o;
            }
        }
        if (tid < 128) {
            *(float4*)(w2s + tid * 4) = *(const float4*)(W2 + tid * 4);
        }
        const float b2v = b2[0];

        const int r  = tid >> 5;          // 0..7
        const int mc = (tid >> 1) & 15;   // 0..15
        const int hh = tid & 1;           // 0..1 (h-half)

        for (int ch = 0; ch < 8; ++ch) {  // 8 chunks of 16 m
            __syncthreads();
            // stage m_part chunk rows [ch*16, ch*16+16)
            {
                const int mr = tid >> 4, cc = tid & 15;
                #pragma unroll
                for (int k = 0; k < 8; ++k) {
                    int h = (cc + k * 16) * 4;
                    *(float4*)(mp + mr * 516 + h) =
                        *(const float4*)(m_part + (size_t)(mbase + ch * 16 + mr) * RELH + h);
                }
            }
            __syncthreads();

            float acc = 0.f;
            const float* qrow = qb  + r  * 516 + hh * 256;
            const float* mrow = mp  + mc * 516 + hh * 256;
            const float* wrow = w2s + hh * 256;
            #pragma unroll 8
            for (int i = 0; i < 64; ++i) {
                float4 qv = *(const float4*)(qrow + i * 4);
                float4 mv = *(const float4*)(mrow + i * 4);
                float4 wv = *(const float4*)(wrow + i * 4);
                acc = fmaf(fmaxf(qv.x + mv.x, 0.f), wv.x, acc);
                acc = fmaf(fmaxf(qv.y + mv.y, 0.f), wv.y, acc);
                acc = fmaf(fmaxf(qv.z + mv.z, 0.f), wv.z, acc);
                acc = fmaf(fmaxf(qv.w + mv.w, 0.f), wv.w, acc);
            }
            acc += __shfl_xor(acc, 1);
            if (hh == 0) {
                float rv = 1.f / (1.f + __expf(-(acc + b2v)));
                rel[r * 128 + ch * 16 + mc] = rv;
            }
        }
    }

    // ---------------- Phase S: scores = (q.k)/32 * relevance ----------------
    {
        __syncthreads();   // protect phase-R scratch reads before overwrite
        float* qs = scratch;                // [8][1024]
        float* ks = scratch + 8 * 1024;     // [4][1032]

        // stage q rows
        {
            const int r2 = tid >> 5, c = tid & 31;
            #pragma unroll
            for (int k = 0; k < 8; ++k) {
                int d = (c + k * 32) * 4;
                *(float4*)(qs + r2 * 1024 + d) =
                    *(const float4*)(queries + (size_t)(rowbase + r2) * DM + d);
            }
        }

        const int r   = tid >> 5;        // 0..7
        const int mcs = (tid >> 3) & 3;  // 0..3
        const int dq  = tid & 7;         // 0..7

        for (int ch = 0; ch < 32; ++ch) {   // 32 chunks of 4 m
            __syncthreads();
            // stage keys rows [ch*4, ch*4+4)
            {
                const int mr = tid >> 6, c = tid & 63;
                #pragma unroll
                for (int k = 0; k < 4; ++k) {
                    int d = (c + k * 64) * 4;
                    *(float4*)(ks + mr * 1032 + d) =
                        *(const float4*)(keys + (size_t)(mbase + ch * 4 + mr) * DM + d);
                }
            }
            __syncthreads();

            float acc = 0.f;
            const float* qrow = qs + r * 1024;
            const float* krow = ks + mcs * 1032;
            #pragma unroll 8
            for (int j = 0; j < 32; ++j) {
                int d = dq * 4 + j * 32;
                float4 qv = *(const float4*)(qrow + d);
                float4 kv = *(const float4*)(krow + d);
                acc = fmaf(qv.x, kv.x, acc);
                acc = fmaf(qv.y, kv.y, acc);
                acc = fmaf(qv.z, kv.z, acc);
                acc = fmaf(qv.w, kv.w, acc);
            }
            acc += __shfl_xor(acc, 1);
            acc += __shfl_xor(acc, 2);
            acc += __shfl_xor(acc, 4);
            if (dq == 0) {
                int m = ch * 4 + mcs;
                rel[r * 128 + m] = acc * 0.03125f * rel[r * 128 + m];
            }
        }
    }

    // ---------------- Softmax over m (128) ----------------
    {
        __syncthreads();
        const int wv = tid >> 6, lane = tid & 63;
        for (int rr = wv * 2; rr < wv * 2 + 2; ++rr) {
            float x0 = rel[rr * 128 + lane];
            float x1 = rel[rr * 128 + 64 + lane];
            float mx = fmaxf(x0, x1);
            #pragma unroll
            for (int d = 1; d < 64; d <<= 1) mx = fmaxf(mx, __shfl_xor(mx, d));
            float e0 = __expf(x0 - mx);
            float e1 = __expf(x1 - mx);
            float ss = e0 + e1;
            #pragma unroll
            for (int d = 1; d < 64; d <<= 1) ss += __shfl_xor(ss, d);
            float inv = 1.f / ss;
            e0 *= inv; e1 *= inv;
            rel[rr * 128 + lane] = e0;
            rel[rr * 128 + 64 + lane] = e1;
            attn_w[(size_t)(rowbase + rr) * MMEM + lane] = e0;
            attn_w[(size_t)(rowbase + rr) * MMEM + 64 + lane] = e1;
        }
    }

    // ---------------- Phase P: attn_out = weights @ values ----------------
    {
        float* vs = scratch;               // [8][1032]
        const int rp = tid >> 5, dg = tid & 31;
        float4 acc[8];
        #pragma unroll
        for (int j = 0; j < 8; ++j) acc[j] = make_float4(0.f, 0.f, 0.f, 0.f);

        for (int ch = 0; ch < 16; ++ch) {   // 16 chunks of 8 m
            __syncthreads();
            {
                const int mr = tid >> 5, c = tid & 31;
                #pragma unroll
                for (int k = 0; k < 8; ++k) {
                    int d = (c + k * 32) * 4;
                    *(float4*)(vs + mr * 1032 + d) =
                        *(const float4*)(values + (size_t)(mbase + ch * 8 + mr) * DM + d);
                }
            }
            __syncthreads();

            #pragma unroll
            for (int mc2 = 0; mc2 < 8; ++mc2) {
                float w = rel[rp * 128 + ch * 8 + mc2];
                #pragma unroll
                for (int j = 0; j < 8; ++j) {
                    float4 v4 = *(const float4*)(vs + mc2 * 1032 + dg * 4 + j * 128);
                    acc[j].x = fmaf(w, v4.x, acc[j].x);
                    acc[j].y = fmaf(w, v4.y, acc[j].y);
                    acc[j].z = fmaf(w, v4.z, acc[j].z);
                    acc[j].w = fmaf(w, v4.w, acc[j].w);
                }
            }
        }
        #pragma unroll
        for (int j = 0; j < 8; ++j) {
            *(float4*)(attn_out + (size_t)(rowbase + rp) * DM + dg * 4 + j * 128) = acc[j];
        }
    }
}

// ---------------------------------------------------------------------------
extern "C" void kernel_launch(void* const* d_in, const int* in_sizes, int n_in,
                              void* d_out, int out_size, void* d_ws, size_t ws_size,
                              hipStream_t stream)
{
    const float* hs  = (const float*)d_in[0];   // (2,1024,1024)
    const float* mem = (const float*)d_in[1];   // (2,128,512)
    const float* Wq  = (const float*)d_in[2];
    const float* bq  = (const float*)d_in[3];
    const float* Wk  = (const float*)d_in[4];
    const float* bk  = (const float*)d_in[5];
    const float* Wv  = (const float*)d_in[6];
    const float* bv  = (const float*)d_in[7];
    const float* Wo  = (const float*)d_in[8];
    const float* bo  = (const float*)d_in[9];
    const float* W1  = (const float*)d_in[10];  // (1536,512)
    const float* b1  = (const float*)d_in[11];
    const float* W2  = (const float*)d_in[12];  // (512,1)
    const float* b2  = (const float*)d_in[13];

    float* out   = (float*)d_out;                       // (2,1024,1024)
    float* attnw = out + (size_t)BATCH * SEQ * DM;      // (2,1024,128)

    float* ws       = (float*)d_ws;
    float* queries  = ws;                                            // 2048*1024
    float* q_part   = queries + (size_t)BATCH * SEQ * DM;            // 2048*512
    float* keys     = q_part  + (size_t)BATCH * SEQ * RELH;          // 256*1024
    float* values   = keys    + (size_t)BATCH * MMEM * DM;           // 256*1024
    float* m_part   = values  + (size_t)BATCH * MMEM * DM;           // 256*512
    float* attn_out = m_part  + (size_t)BATCH * MMEM * RELH;         // 2048*1024

    const float* W1q = W1;                       // rows [0,1024)
    const float* W1m = W1 + (size_t)DM * RELH;   // rows [1024,1536)

    dim3 blk(256);

    // queries = hs @ Wq + bq
    gemm_f32<<<dim3(DM / 64, (BATCH * SEQ) / 64), blk, 0, stream>>>(
        hs, Wq, bq, queries, DM, DM);
    // keys = mem @ Wk + bk ; values = mem @ Wv + bv ; m_part = mem @ W1m
    gemm_f32<<<dim3(DM / 64, (BATCH * MMEM) / 64), blk, 0, stream>>>(
        mem, Wk, bk, keys, DM, MEMD);
    gemm_f32<<<dim3(DM / 64, (BATCH * MMEM) / 64), blk, 0, stream>>>(
        mem, Wv, bv, values, DM, MEMD);
    gemm_f32<<<dim3(RELH / 64, (BATCH * MMEM) / 64), blk, 0, stream>>>(
        mem, W1m, nullptr, m_part, RELH, MEMD);
    // q_part = queries @ W1q
    gemm_f32<<<dim3(RELH / 64, (BATCH * SEQ) / 64), blk, 0, stream>>>(
        queries, W1q, nullptr, q_part, RELH, DM);
    // fused relevance/scores/softmax/PV
    fused_attn<<<dim3((BATCH * SEQ) / TR), blk, 0, stream>>>(
        q_part, m_part, queries, keys, values, W2, b1, b2, attn_out, attnw);
    // out = attn_out @ Wo + bo
    gemm_f32<<<dim3(DM / 64, (BATCH * SEQ) / 64), blk, 0, stream>>>(
        attn_out, Wo, bo, out, DM, DM);
}

// Round 3
// 246.733 us; speedup vs baseline: 1.5154x; 1.5154x over previous
//
#include <hip/hip_runtime.h>
#include <hip/hip_bf16.h>
#include <math.h>

// Problem constants (fixed by reference)
#define BATCH 2
#define SEQ   1024
#define DM    1024   // D_MODEL
#define MMEM  128    // memory slots
#define MEMD  512    // MEM_DIM
#define RELH  512    // REL_HID

typedef __attribute__((ext_vector_type(8))) short   bf16x8;
typedef __attribute__((ext_vector_type(4))) float   f32x4;

__device__ inline unsigned short f2bf(float f) {
    union { float f; unsigned u; } v; v.f = f;
    unsigned r = v.u + 0x7fff + ((v.u >> 16) & 1);   // RNE
    return (unsigned short)(r >> 16);
}
__device__ inline float bf2f(unsigned short u) {
    union { unsigned u; float f; } v; v.u = ((unsigned)u) << 16;
    return v.f;
}

// ---------------------------------------------------------------------------
// cast fp32 -> bf16, 8 elems/thread
// ---------------------------------------------------------------------------
__global__ __launch_bounds__(256) void cast_f32_bf16(
    const float* __restrict__ in, unsigned short* __restrict__ out, int n8)
{
    int i = blockIdx.x * 256 + threadIdx.x;
    if (i >= n8) return;
    const float4* p = (const float4*)in + (size_t)i * 2;
    float4 a = p[0], b = p[1];
    ushort4 u0 = { f2bf(a.x), f2bf(a.y), f2bf(a.z), f2bf(a.w) };
    ushort4 u1 = { f2bf(b.x), f2bf(b.y), f2bf(b.z), f2bf(b.w) };
    ushort4* q = (ushort4*)(out + (size_t)i * 8);
    q[0] = u0; q[1] = u1;
}

// ---------------------------------------------------------------------------
// transpose-cast: out[c][r] = bf16(in[r][c]); in R x C fp32 (row-major),
// out C x R bf16. R,C multiples of 64. grid (C/64, R/64), 256 threads.
// ---------------------------------------------------------------------------
__global__ __launch_bounds__(256) void transpose_cast(
    const float* __restrict__ in, unsigned short* __restrict__ out, int R, int C)
{
    __shared__ float t[64][65];
    const int r0 = blockIdx.y * 64, c0 = blockIdx.x * 64;
    const int tid = threadIdx.x;
    #pragma unroll
    for (int i = 0; i < 16; ++i) {
        int idx = tid + 256 * i;          // 0..4095
        int r = idx >> 6, c = idx & 63;
        t[c][r] = in[(size_t)(r0 + r) * C + c0 + c];
    }
    __syncthreads();
    #pragma unroll
    for (int i = 0; i < 16; ++i) {
        int idx = tid + 256 * i;
        int ro = idx >> 6, co = idx & 63;
        out[(size_t)(c0 + ro) * R + r0 + co] = f2bf(t[ro][co]);
    }
}

// ---------------------------------------------------------------------------
// bf16 MFMA GEMM: C(f32, optional) / C2(bf16, optional) = A @ Bt^T + bias
//   A : [M][K] bf16 row-major, Bt : [N][K] bf16 row-major (i.e. B transposed)
// Tile BM=64, BN=128, BK=64. 256 threads = 4 waves; wave w covers all 64 rows
// x 32 cols (cols w*32..w*32+31): frags mr=0..3, nr=0..1, mfma 16x16x32.
// LDS rows padded to 72 bf16 (144 B): frag reads AND staging writes are
// bank-uniform. Reg-staged double buffer (2-barrier loop).
// grid (N/128, M/64).
// ---------------------------------------------------------------------------
__global__ __launch_bounds__(256) void gemm_bf16(
    const unsigned short* __restrict__ A, const unsigned short* __restrict__ Bt,
    const float* __restrict__ bias, float* __restrict__ C,
    unsigned short* __restrict__ C2, int N, int K)
{
    __shared__ unsigned short Al[64 * 72];
    __shared__ unsigned short Bl[128 * 72];

    const int tid  = threadIdx.x;
    const int lane = tid & 63;
    const int wid  = tid >> 6;
    const size_t row0 = (size_t)blockIdx.y * 64;
    const size_t col0 = (size_t)blockIdx.x * 128;

    // staging chunk indices (16B = 8 bf16 chunks; 8 chunks per 64-k row)
    // A: 512 chunks -> thread handles idx = tid, tid+256
    // B: 1024 chunks -> idx = tid + 256*i, i<4
    const int ar_[2] = { tid >> 3, (tid + 256) >> 3 };
    const int ac_[2] = { tid & 7, tid & 7 };
    int br_[4], bc_[4];
    #pragma unroll
    for (int i = 0; i < 4; ++i) { int idx = tid + 256 * i; br_[i] = idx >> 3; bc_[i] = idx & 7; }

    f32x4 acc[4][2];
    #pragma unroll
    for (int m = 0; m < 4; ++m)
        #pragma unroll
        for (int n = 0; n < 2; ++n) acc[m][n] = (f32x4){0.f, 0.f, 0.f, 0.f};

    bf16x8 ar[2], br[4];
    // prefetch k-tile 0
    #pragma unroll
    for (int j = 0; j < 2; ++j)
        ar[j] = *(const bf16x8*)(A + (row0 + ar_[j]) * K + ac_[j] * 8);
    #pragma unroll
    for (int j = 0; j < 4; ++j)
        br[j] = *(const bf16x8*)(Bt + (col0 + br_[j]) * K + bc_[j] * 8);

    const int nk = K >> 6;
    for (int kt = 0; kt < nk; ++kt) {
        __syncthreads();   // previous tile fully consumed
        #pragma unroll
        for (int j = 0; j < 2; ++j)
            *(bf16x8*)(Al + ar_[j] * 72 + ac_[j] * 8) = ar[j];
        #pragma unroll
        for (int j = 0; j < 4; ++j)
            *(bf16x8*)(Bl + br_[j] * 72 + bc_[j] * 8) = br[j];
        __syncthreads();   // tile visible to all waves

        if (kt + 1 < nk) {
            const int k0 = (kt + 1) << 6;
            #pragma unroll
            for (int j = 0; j < 2; ++j)
                ar[j] = *(const bf16x8*)(A + (row0 + ar_[j]) * K + k0 + ac_[j] * 8);
            #pragma unroll
            for (int j = 0; j < 4; ++j)
                br[j] = *(const bf16x8*)(Bt + (col0 + br_[j]) * K + k0 + bc_[j] * 8);
        }

        #pragma unroll
        for (int kk = 0; kk < 2; ++kk) {
            bf16x8 af[4], bfr[2];
            const int ko = kk * 32 + (lane >> 4) * 8;
            #pragma unroll
            for (int m = 0; m < 4; ++m)
                af[m] = *(const bf16x8*)(Al + (m * 16 + (lane & 15)) * 72 + ko);
            #pragma unroll
            for (int n = 0; n < 2; ++n)
                bfr[n] = *(const bf16x8*)(Bl + (wid * 32 + n * 16 + (lane & 15)) * 72 + ko);
            #pragma unroll
            for (int m = 0; m < 4; ++m)
                #pragma unroll
                for (int n = 0; n < 2; ++n)
                    acc[m][n] = __builtin_amdgcn_mfma_f32_16x16x32_bf16(
                        af[m], bfr[n], acc[m][n], 0, 0, 0);
        }
    }

    // epilogue: C/D layout col = lane&15, row = (lane>>4)*4 + j  [m89/m91]
    const int cr = lane >> 4, cc = lane & 15;
    #pragma unroll
    for (int n = 0; n < 2; ++n) {
        const size_t col = col0 + wid * 32 + n * 16 + cc;
        const float bv = bias ? bias[col] : 0.f;
        #pragma unroll
        for (int m = 0; m < 4; ++m) {
            #pragma unroll
            for (int j = 0; j < 4; ++j) {
                const size_t row = row0 + m * 16 + cr * 4 + j;
                const float v = acc[m][n][j] + bv;
                if (C)  C[row * N + col] = v;
                if (C2) C2[row * N + col] = f2bf(v);
            }
        }
    }
}

// ---------------------------------------------------------------------------
// fp32 tiled GEMM for the three small (M=256) projections — unchanged.
// ---------------------------------------------------------------------------
__global__ __launch_bounds__(256) void gemm_f32(
    const float* __restrict__ A, const float* __restrict__ W,
    const float* __restrict__ bias, float* __restrict__ C,
    int N, int K)
{
    __shared__ float As[16][68];
    __shared__ float Bs[16][64];

    const int tid = threadIdx.x;
    const int tx = tid & 15;
    const int ty = tid >> 4;
    const size_t row0 = blockIdx.y * 64;
    const size_t col0 = blockIdx.x * 64;

    const int arow = tid >> 2;
    const int akq  = (tid & 3) * 4;
    const int bkr  = tid >> 4;
    const int bnq  = (tid & 15) * 4;

    float acc[4][4];
    #pragma unroll
    for (int i = 0; i < 4; ++i)
        #pragma unroll
        for (int j = 0; j < 4; ++j) acc[i][j] = 0.f;

    for (int k0 = 0; k0 < K; k0 += 16) {
        __syncthreads();
        {
            float4 av = *(const float4*)(A + (row0 + arow) * (size_t)K + k0 + akq);
            As[akq + 0][arow] = av.x;
            As[akq + 1][arow] = av.y;
            As[akq + 2][arow] = av.z;
            As[akq + 3][arow] = av.w;
        }
        {
            *(float4*)(&Bs[bkr][bnq]) =
                *(const float4*)(W + (size_t)(k0 + bkr) * N + col0 + bnq);
        }
        __syncthreads();

        #pragma unroll
        for (int kk = 0; kk < 16; ++kk) {
            float4 a4 = *(const float4*)(&As[kk][ty * 4]);
            float4 b4 = *(const float4*)(&Bs[kk][tx * 4]);
            float a[4] = {a4.x, a4.y, a4.z, a4.w};
            float b[4] = {b4.x, b4.y, b4.z, b4.w};
            #pragma unroll
            for (int i = 0; i < 4; ++i)
                #pragma unroll
                for (int j = 0; j < 4; ++j)
                    acc[i][j] = fmaf(a[i], b[j], acc[i][j]);
        }
    }

    float4 bb = make_float4(0.f, 0.f, 0.f, 0.f);
    if (bias) bb = *(const float4*)(bias + col0 + tx * 4);
    #pragma unroll
    for (int i = 0; i < 4; ++i) {
        float4 c4;
        c4.x = acc[i][0] + bb.x;
        c4.y = acc[i][1] + bb.y;
        c4.z = acc[i][2] + bb.z;
        c4.w = acc[i][3] + bb.w;
        *(float4*)(C + (row0 + ty * 4 + i) * (size_t)N + col0 + tx * 4) = c4;
    }
}

// ---------------------------------------------------------------------------
// Fused relevance -> scores -> softmax -> PV (structure unchanged from R2;
// queries now read as bf16, attn_out written as bf16 for the out-GEMM).
// ---------------------------------------------------------------------------
#define TR 8
__global__ __launch_bounds__(256) void fused_attn(
    const float* __restrict__ q_part,            // (B*S, 512) f32
    const float* __restrict__ m_part,            // (B*M, 512) f32
    const unsigned short* __restrict__ queries,  // (B*S, 1024) bf16
    const float* __restrict__ keys,              // (B*M, 1024) f32
    const float* __restrict__ values,            // (B*M, 1024) f32
    const float* __restrict__ W2,                // (512)
    const float* __restrict__ b1,                // (512)
    const float* __restrict__ b2,                // (1)
    unsigned short* __restrict__ attn_out,       // (B*S, 1024) bf16
    float* __restrict__ attn_w)                  // (B*S, 128) f32
{
    __shared__ __align__(16) float sm[13920];
    float* rel = sm;               // [8][128] persistent
    float* scratch = sm + 1024;

    const int tid = threadIdx.x;
    const int bidx = blockIdx.x;
    const int b = bidx >> 7;
    const int s0 = (bidx & 127) * TR;
    const int rowbase = b * SEQ + s0;
    const int mbase = b * MMEM;

    // ---------------- Phase R: relevance ----------------
    {
        float* qb  = scratch;
        float* mp  = qb + 8 * 516;
        float* w2s = mp + 16 * 516;

        {
            const int r = tid >> 5, c = tid & 31;
            #pragma unroll
            for (int k = 0; k < 4; ++k) {
                int h = (c + k * 32) * 4;
                float4 v  = *(const float4*)(q_part + (size_t)(rowbase + r) * RELH + h);
                float4 bv = *(const float4*)(b1 + h);
                float4 o;
                o.x = v.x + bv.x; o.y = v.y + bv.y; o.z = v.z + bv.z; o.w = v.w + bv.w;
                *(float4*)(qb + r * 516 + h) = o;
            }
        }
        if (tid < 128) {
            *(float4*)(w2s + tid * 4) = *(const float4*)(W2 + tid * 4);
        }
        const float b2v = b2[0];

        const int r  = tid >> 5;
        const int mc = (tid >> 1) & 15;
        const int hh = tid & 1;

        for (int ch = 0; ch < 8; ++ch) {
            __syncthreads();
            {
                const int mr = tid >> 4, cc = tid & 15;
                #pragma unroll
                for (int k = 0; k < 8; ++k) {
                    int h = (cc + k * 16) * 4;
                    *(float4*)(mp + mr * 516 + h) =
                        *(const float4*)(m_part + (size_t)(mbase + ch * 16 + mr) * RELH + h);
                }
            }
            __syncthreads();

            float acc = 0.f;
            const float* qrow = qb  + r  * 516 + hh * 256;
            const float* mrow = mp  + mc * 516 + hh * 256;
            const float* wrow = w2s + hh * 256;
            #pragma unroll 8
            for (int i = 0; i < 64; ++i) {
                float4 qv = *(const float4*)(qrow + i * 4);
                float4 mv = *(const float4*)(mrow + i * 4);
                float4 wv = *(const float4*)(wrow + i * 4);
                acc = fmaf(fmaxf(qv.x + mv.x, 0.f), wv.x, acc);
                acc = fmaf(fmaxf(qv.y + mv.y, 0.f), wv.y, acc);
                acc = fmaf(fmaxf(qv.z + mv.z, 0.f), wv.z, acc);
                acc = fmaf(fmaxf(qv.w + mv.w, 0.f), wv.w, acc);
            }
            acc += __shfl_xor(acc, 1);
            if (hh == 0) {
                float rv = 1.f / (1.f + __expf(-(acc + b2v)));
                rel[r * 128 + ch * 16 + mc] = rv;
            }
        }
    }

    // ---------------- Phase S: scores = (q.k)/32 * relevance ----------------
    {
        __syncthreads();
        float* qs = scratch;                // [8][1024]
        float* ks = scratch + 8 * 1024;     // [4][1032]

        // stage q rows (bf16 -> f32)
        {
            const int r2 = tid >> 5, c = tid & 31;
            #pragma unroll
            for (int k = 0; k < 4; ++k) {
                int d = (c + k * 32) * 8;
                bf16x8 v = *(const bf16x8*)(queries + (size_t)(rowbase + r2) * DM + d);
                float4 f0 = { bf2f((unsigned short)v[0]), bf2f((unsigned short)v[1]),
                              bf2f((unsigned short)v[2]), bf2f((unsigned short)v[3]) };
                float4 f1 = { bf2f((unsigned short)v[4]), bf2f((unsigned short)v[5]),
                              bf2f((unsigned short)v[6]), bf2f((unsigned short)v[7]) };
                *(float4*)(qs + r2 * 1024 + d)     = f0;
                *(float4*)(qs + r2 * 1024 + d + 4) = f1;
            }
        }

        const int r   = tid >> 5;
        const int mcs = (tid >> 3) & 3;
        const int dq  = tid & 7;

        for (int ch = 0; ch < 32; ++ch) {
            __syncthreads();
            {
                const int mr = tid >> 6, c = tid & 63;
                #pragma unroll
                for (int k = 0; k < 4; ++k) {
                    int d = (c + k * 64) * 4;
                    *(float4*)(ks + mr * 1032 + d) =
                        *(const float4*)(keys + (size_t)(mbase + ch * 4 + mr) * DM + d);
                }
            }
            __syncthreads();

            float acc = 0.f;
            const float* qrow = qs + r * 1024;
            const float* krow = ks + mcs * 1032;
            #pragma unroll 8
            for (int j = 0; j < 32; ++j) {
                int d = dq * 4 + j * 32;
                float4 qv = *(const float4*)(qrow + d);
                float4 kv = *(const float4*)(krow + d);
                acc = fmaf(qv.x, kv.x, acc);
                acc = fmaf(qv.y, kv.y, acc);
                acc = fmaf(qv.z, kv.z, acc);
                acc = fmaf(qv.w, kv.w, acc);
            }
            acc += __shfl_xor(acc, 1);
            acc += __shfl_xor(acc, 2);
            acc += __shfl_xor(acc, 4);
            if (dq == 0) {
                int m = ch * 4 + mcs;
                rel[r * 128 + m] = acc * 0.03125f * rel[r * 128 + m];
            }
        }
    }

    // ---------------- Softmax over m (128) ----------------
    {
        __syncthreads();
        const int wv = tid >> 6, lane = tid & 63;
        for (int rr = wv * 2; rr < wv * 2 + 2; ++rr) {
            float x0 = rel[rr * 128 + lane];
            float x1 = rel[rr * 128 + 64 + lane];
            float mx = fmaxf(x0, x1);
            #pragma unroll
            for (int d = 1; d < 64; d <<= 1) mx = fmaxf(mx, __shfl_xor(mx, d));
            float e0 = __expf(x0 - mx);
            float e1 = __expf(x1 - mx);
            float ss = e0 + e1;
            #pragma unroll
            for (int d = 1; d < 64; d <<= 1) ss += __shfl_xor(ss, d);
            float inv = 1.f / ss;
            e0 *= inv; e1 *= inv;
            rel[rr * 128 + lane] = e0;
            rel[rr * 128 + 64 + lane] = e1;
            attn_w[(size_t)(rowbase + rr) * MMEM + lane] = e0;
            attn_w[(size_t)(rowbase + rr) * MMEM + 64 + lane] = e1;
        }
    }

    // ---------------- Phase P: attn_out = weights @ values (bf16 out) -------
    {
        float* vs = scratch;               // [8][1032]
        const int rp = tid >> 5, dg = tid & 31;
        float4 acc[8];
        #pragma unroll
        for (int j = 0; j < 8; ++j) acc[j] = make_float4(0.f, 0.f, 0.f, 0.f);

        for (int ch = 0; ch < 16; ++ch) {
            __syncthreads();
            {
                const int mr = tid >> 5, c = tid & 31;
                #pragma unroll
                for (int k = 0; k < 8; ++k) {
                    int d = (c + k * 32) * 4;
                    *(float4*)(vs + mr * 1032 + d) =
                        *(const float4*)(values + (size_t)(mbase + ch * 8 + mr) * DM + d);
                }
            }
            __syncthreads();

            #pragma unroll
            for (int mc2 = 0; mc2 < 8; ++mc2) {
                float w = rel[rp * 128 + ch * 8 + mc2];
                #pragma unroll
                for (int j = 0; j < 8; ++j) {
                    float4 v4 = *(const float4*)(vs + mc2 * 1032 + dg * 4 + j * 128);
                    acc[j].x = fmaf(w, v4.x, acc[j].x);
                    acc[j].y = fmaf(w, v4.y, acc[j].y);
                    acc[j].z = fmaf(w, v4.z, acc[j].z);
                    acc[j].w = fmaf(w, v4.w, acc[j].w);
                }
            }
        }
        #pragma unroll
        for (int j = 0; j < 8; ++j) {
            ushort4 u = { f2bf(acc[j].x), f2bf(acc[j].y), f2bf(acc[j].z), f2bf(acc[j].w) };
            *(ushort4*)(attn_out + (size_t)(rowbase + rp) * DM + dg * 4 + j * 128) = u;
        }
    }
}

// ---------------------------------------------------------------------------
extern "C" void kernel_launch(void* const* d_in, const int* in_sizes, int n_in,
                              void* d_out, int out_size, void* d_ws, size_t ws_size,
                              hipStream_t stream)
{
    const float* hs  = (const float*)d_in[0];
    const float* mem = (const float*)d_in[1];
    const float* Wq  = (const float*)d_in[2];
    const float* bq  = (const float*)d_in[3];
    const float* Wk  = (const float*)d_in[4];
    const float* bk  = (const float*)d_in[5];
    const float* Wv  = (const float*)d_in[6];
    const float* bv  = (const float*)d_in[7];
    const float* Wo  = (const float*)d_in[8];
    const float* bo  = (const float*)d_in[9];
    const float* W1  = (const float*)d_in[10];  // (1536,512); rows [0,1024) = W1q
    const float* b1  = (const float*)d_in[11];
    const float* W2  = (const float*)d_in[12];
    const float* b2  = (const float*)d_in[13];

    float* out   = (float*)d_out;                       // (2,1024,1024)
    float* attnw = out + (size_t)BATCH * SEQ * DM;      // (2,1024,128)

    // ws layout (bytes): f32 buffers then bf16 buffers. Total ~19.5 MB.
    char* w = (char*)d_ws;
    float* q_part = (float*)w;                        w += (size_t)BATCH * SEQ * RELH * 4;   // 4 MB
    float* keys   = (float*)w;                        w += (size_t)BATCH * MMEM * DM * 4;    // 1 MB
    float* values = (float*)w;                        w += (size_t)BATCH * MMEM * DM * 4;    // 1 MB
    float* m_part = (float*)w;                        w += (size_t)BATCH * MMEM * RELH * 4;  // 0.5 MB
    unsigned short* queries_bf = (unsigned short*)w;  w += (size_t)BATCH * SEQ * DM * 2;     // 4 MB
    unsigned short* bfA        = (unsigned short*)w;  w += (size_t)BATCH * SEQ * DM * 2;     // 4 MB (hs_bf, then attn_out_bf)
    unsigned short* Wq_t       = (unsigned short*)w;  w += (size_t)DM * DM * 2;              // 2 MB
    unsigned short* W1q_t      = (unsigned short*)w;  w += (size_t)DM * RELH * 2;            // 1 MB
    unsigned short* Wo_t       = (unsigned short*)w;  w += (size_t)DM * DM * 2;              // 2 MB

    unsigned short* hs_bf       = bfA;   // consumed by gemm1, then buffer is reused
    unsigned short* attn_out_bf = bfA;   // written by fused_attn (after gemm1)

    dim3 blk(256);

    // casts / weight transposes
    cast_f32_bf16<<<dim3((BATCH * SEQ * DM) / (256 * 8)), blk, 0, stream>>>(
        hs, hs_bf, (BATCH * SEQ * DM) / 8);
    transpose_cast<<<dim3(DM / 64, DM / 64), blk, 0, stream>>>(Wq, Wq_t, DM, DM);
    transpose_cast<<<dim3(RELH / 64, DM / 64), blk, 0, stream>>>(W1, W1q_t, DM, RELH);
    transpose_cast<<<dim3(DM / 64, DM / 64), blk, 0, stream>>>(Wo, Wo_t, DM, DM);

    // queries(bf16) = hs @ Wq + bq
    gemm_bf16<<<dim3(DM / 128, (BATCH * SEQ) / 64), blk, 0, stream>>>(
        hs_bf, Wq_t, bq, nullptr, queries_bf, DM, DM);

    // small fp32 projections (M=256)
    gemm_f32<<<dim3(DM / 64, (BATCH * MMEM) / 64), blk, 0, stream>>>(
        mem, Wk, bk, keys, DM, MEMD);
    gemm_f32<<<dim3(DM / 64, (BATCH * MMEM) / 64), blk, 0, stream>>>(
        mem, Wv, bv, values, DM, MEMD);
    gemm_f32<<<dim3(RELH / 64, (BATCH * MMEM) / 64), blk, 0, stream>>>(
        mem, W1 + (size_t)DM * RELH, nullptr, m_part, RELH, MEMD);

    // q_part(f32) = queries_bf @ W1q
    gemm_bf16<<<dim3(RELH / 128, (BATCH * SEQ) / 64), blk, 0, stream>>>(
        queries_bf, W1q_t, nullptr, q_part, nullptr, RELH, DM);

    // fused relevance/scores/softmax/PV -> attn_out_bf, attnw
    fused_attn<<<dim3((BATCH * SEQ) / TR), blk, 0, stream>>>(
        q_part, m_part, queries_bf, keys, values, W2, b1, b2, attn_out_bf, attnw);

    // out = attn_out @ Wo + bo
    gemm_bf16<<<dim3(DM / 128, (BATCH * SEQ) / 64), blk, 0, stream>>>(
        attn_out_bf, Wo_t, bo, out, nullptr, DM, DM);
}

// Round 4
// 137.326 us; speedup vs baseline: 2.7228x; 1.7967x over previous
//
#include <hip/hip_runtime.h>
#include <math.h>

// Problem constants (fixed by reference)
#define BATCH 2
#define SEQ   1024
#define DM    1024   // D_MODEL
#define MMEM  128    // memory slots
#define MEMD  512    // MEM_DIM
#define RELH  512    // REL_HID

typedef _Float16 f16;
typedef __attribute__((ext_vector_type(2))) _Float16 f16x2;
typedef __attribute__((ext_vector_type(4))) _Float16 f16x4;
typedef __attribute__((ext_vector_type(8))) _Float16 f16x8;
typedef __attribute__((ext_vector_type(4))) float    f32x4;

__device__ inline float dot2acc(f16x2 a, f16x2 b, float c) {
#if __has_builtin(__builtin_amdgcn_fdot2)
    return __builtin_amdgcn_fdot2(a, b, c, false);
#else
    return c + (float)a[0] * (float)b[0] + (float)a[1] * (float)b[1];
#endif
}
__device__ inline f16x2 relu2(f16x2 a) {
    f16x2 z = { (_Float16)0.0f, (_Float16)0.0f };
#if __has_builtin(__builtin_elementwise_max)
    return __builtin_elementwise_max(a, z);
#else
    f16x2 r;
    r[0] = a[0] > z[0] ? a[0] : z[0];
    r[1] = a[1] > z[1] ? a[1] : z[1];
    return r;
#endif
}

// ---------------------------------------------------------------------------
// cast fp32 -> fp16, 8 elems/thread
// ---------------------------------------------------------------------------
__global__ __launch_bounds__(256) void cast_f32_f16(
    const float* __restrict__ in, f16* __restrict__ out, int n8)
{
    int i = blockIdx.x * 256 + threadIdx.x;
    if (i >= n8) return;
    const float4* p = (const float4*)in + (size_t)i * 2;
    float4 a = p[0], b = p[1];
    f16x8 v = { (f16)a.x, (f16)a.y, (f16)a.z, (f16)a.w,
                (f16)b.x, (f16)b.y, (f16)b.z, (f16)b.w };
    *(f16x8*)(out + (size_t)i * 8) = v;
}

// ---------------------------------------------------------------------------
// transpose-cast: out[c][r] = f16(in[r][c]); in R x C fp32 row-major.
// grid (C/64, R/64), 256 threads.
// ---------------------------------------------------------------------------
__global__ __launch_bounds__(256) void transpose_cast(
    const float* __restrict__ in, f16* __restrict__ out, int R, int C)
{
    __shared__ float t[64][65];
    const int r0 = blockIdx.y * 64, c0 = blockIdx.x * 64;
    const int tid = threadIdx.x;
    #pragma unroll
    for (int i = 0; i < 16; ++i) {
        int idx = tid + 256 * i;
        int r = idx >> 6, c = idx & 63;
        t[c][r] = in[(size_t)(r0 + r) * C + c0 + c];
    }
    __syncthreads();
    #pragma unroll
    for (int i = 0; i < 16; ++i) {
        int idx = tid + 256 * i;
        int ro = idx >> 6, co = idx & 63;
        out[(size_t)(c0 + ro) * R + r0 + co] = (f16)t[ro][co];
    }
}

// ---------------------------------------------------------------------------
// fp16 MFMA GEMM: C(f32, opt) / C2(f16, opt) = A @ Bt^T + bias
//   A : [M][K] f16 row-major, Bt : [N][K] f16 row-major.
// BM=64, BN=128, BK=64. 256 threads = 4 waves. 72-f16-padded LDS rows.
// grid (N/128, M/64).
// ---------------------------------------------------------------------------
__global__ __launch_bounds__(256) void gemm_h(
    const f16* __restrict__ A, const f16* __restrict__ Bt,
    const float* __restrict__ bias, float* __restrict__ C,
    f16* __restrict__ C2, int N, int K)
{
    __shared__ f16 Al[64 * 72];
    __shared__ f16 Bl[128 * 72];

    const int tid  = threadIdx.x;
    const int lane = tid & 63;
    const int wid  = tid >> 6;
    const size_t row0 = (size_t)blockIdx.y * 64;
    const size_t col0 = (size_t)blockIdx.x * 128;

    const int ar_[2] = { tid >> 3, (tid + 256) >> 3 };
    const int ac_ = tid & 7;
    int br_[4];
    #pragma unroll
    for (int i = 0; i < 4; ++i) br_[i] = (tid + 256 * i) >> 3;

    f32x4 acc[4][2];
    #pragma unroll
    for (int m = 0; m < 4; ++m)
        #pragma unroll
        for (int n = 0; n < 2; ++n) acc[m][n] = (f32x4){0.f, 0.f, 0.f, 0.f};

    f16x8 ar[2], br[4];
    #pragma unroll
    for (int j = 0; j < 2; ++j)
        ar[j] = *(const f16x8*)(A + (row0 + ar_[j]) * K + ac_ * 8);
    #pragma unroll
    for (int j = 0; j < 4; ++j)
        br[j] = *(const f16x8*)(Bt + (col0 + br_[j]) * K + ac_ * 8);

    const int nk = K >> 6;
    for (int kt = 0; kt < nk; ++kt) {
        __syncthreads();
        #pragma unroll
        for (int j = 0; j < 2; ++j)
            *(f16x8*)(Al + ar_[j] * 72 + ac_ * 8) = ar[j];
        #pragma unroll
        for (int j = 0; j < 4; ++j)
            *(f16x8*)(Bl + br_[j] * 72 + ac_ * 8) = br[j];
        __syncthreads();

        if (kt + 1 < nk) {
            const int k0 = (kt + 1) << 6;
            #pragma unroll
            for (int j = 0; j < 2; ++j)
                ar[j] = *(const f16x8*)(A + (row0 + ar_[j]) * K + k0 + ac_ * 8);
            #pragma unroll
            for (int j = 0; j < 4; ++j)
                br[j] = *(const f16x8*)(Bt + (col0 + br_[j]) * K + k0 + ac_ * 8);
        }

        #pragma unroll
        for (int kk = 0; kk < 2; ++kk) {
            f16x8 af[4], bfr[2];
            const int ko = kk * 32 + (lane >> 4) * 8;
            #pragma unroll
            for (int m = 0; m < 4; ++m)
                af[m] = *(const f16x8*)(Al + (m * 16 + (lane & 15)) * 72 + ko);
            #pragma unroll
            for (int n = 0; n < 2; ++n)
                bfr[n] = *(const f16x8*)(Bl + (wid * 32 + n * 16 + (lane & 15)) * 72 + ko);
            #pragma unroll
            for (int m = 0; m < 4; ++m)
                #pragma unroll
                for (int n = 0; n < 2; ++n)
                    acc[m][n] = __builtin_amdgcn_mfma_f32_16x16x32_f16(
                        af[m], bfr[n], acc[m][n], 0, 0, 0);
        }
    }

    // C/D layout: col = lane&15, row = (lane>>4)*4 + j
    const int cr = lane >> 4, cc = lane & 15;
    #pragma unroll
    for (int n = 0; n < 2; ++n) {
        const size_t col = col0 + wid * 32 + n * 16 + cc;
        const float bvv = bias ? bias[col] : 0.f;
        #pragma unroll
        for (int m = 0; m < 4; ++m) {
            #pragma unroll
            for (int j = 0; j < 4; ++j) {
                const size_t row = row0 + m * 16 + cr * 4 + j;
                const float v = acc[m][n][j] + bvv;
                if (C)  C[row * N + col] = v;
                if (C2) C2[row * N + col] = (f16)v;
            }
        }
    }
}

// ---------------------------------------------------------------------------
// m_part [256][512] f16 -> mpt [b][h2][m][2] f16 (h-pair-major transpose).
// grid 8 = (b, 128-h chunk). 256 threads.
// ---------------------------------------------------------------------------
__global__ __launch_bounds__(256) void mpt_kernel(
    const f16* __restrict__ m_part, f16* __restrict__ mpt)
{
    __shared__ f16 t[128][136];
    const int b = blockIdx.x >> 2, hc = blockIdx.x & 3;
    const int tid = threadIdx.x;
    #pragma unroll
    for (int k = 0; k < 8; ++k) {
        int idx = tid + 256 * k;
        int m = idx >> 4, hs_ = idx & 15;
        *(f16x8*)(&t[m][hs_ * 8]) =
            *(const f16x8*)(m_part + (size_t)(b * 128 + m) * 512 + hc * 128 + hs_ * 8);
    }
    __syncthreads();
    #pragma unroll
    for (int k = 0; k < 32; ++k) {
        int idx = tid + 256 * k;
        int h2l = idx >> 7, m = idx & 127;
        f16x2 v = { t[m][h2l * 2], t[m][h2l * 2 + 1] };
        *(f16x2*)(mpt + ((size_t)b * 256 + hc * 64 + h2l) * 256 + m * 2) = v;
    }
}

// ---------------------------------------------------------------------------
// relevance_kernel: rel[b,s,m] = sigmoid(sum_h relu(qp[s,h]+mp[m,h])*w2[h] + b2)
// (b1 folded into m_part by its GEMM bias.)
// grid 256 = (b, 8-s tile). 256 thr = 4 waves; wave=2 s-rows, lane=2 m.
// ---------------------------------------------------------------------------
__global__ __launch_bounds__(256) void relevance_kernel(
    const f16* __restrict__ q_part,  // [2048][512]
    const f16* __restrict__ mpt,     // [b][256 h2][128 m][2]
    const float* __restrict__ W2,    // [512]
    const float* __restrict__ b2,    // [1]
    float* __restrict__ rel)         // [2048][128]
{
    __shared__ f16 qs[8 * 512];      // 8 KB
    __shared__ f16 mps[64 * 256];    // [64 h2][128 m][2], 32 KB
    __shared__ f16 w2s[512];         // 1 KB

    const int tid = threadIdx.x;
    const int b = blockIdx.x >> 7, st = blockIdx.x & 127;
    const size_t rowbase = (size_t)b * SEQ + st * 8;

    {
        int r = tid >> 5, c = tid & 31;
        const f16* src = q_part + (rowbase + r) * 512 + c * 16;
        *(f16x8*)(qs + r * 512 + c * 16)     = *(const f16x8*)(src);
        *(f16x8*)(qs + r * 512 + c * 16 + 8) = *(const f16x8*)(src + 8);
    }
    if (tid < 128) {
        float4 w4 = *(const float4*)(W2 + tid * 4);
        f16x4 hv = { (f16)w4.x, (f16)w4.y, (f16)w4.z, (f16)w4.w };
        *(f16x4*)(w2s + tid * 4) = hv;
    }
    const float b2v = b2[0];
    const int sg = tid >> 6, lane = tid & 63;

    float acc00 = 0.f, acc01 = 0.f, acc10 = 0.f, acc11 = 0.f;
    const f16* mptb = mpt + (size_t)b * 65536;

    for (int hc = 0; hc < 4; ++hc) {
        __syncthreads();
        {
            const f16x8* src = (const f16x8*)(mptb + hc * 16384);
            f16x8* dst = (f16x8*)mps;
            #pragma unroll
            for (int k = 0; k < 8; ++k) dst[tid + 256 * k] = src[tid + 256 * k];
        }
        __syncthreads();

        #pragma unroll 4
        for (int step = 0; step < 16; ++step) {
            const int habs = hc * 128 + step * 8;
            uint4 q0u = *(const uint4*)(qs + (2 * sg) * 512 + habs);
            uint4 q1u = *(const uint4*)(qs + (2 * sg + 1) * 512 + habs);
            uint4 wu  = *(const uint4*)(w2s + habs);
            const unsigned* q0p = (const unsigned*)&q0u;
            const unsigned* q1p = (const unsigned*)&q1u;
            const unsigned* wp_ = (const unsigned*)&wu;
            #pragma unroll
            for (int jj = 0; jj < 4; ++jj) {
                uint2 mpu = *(const uint2*)(mps + ((step * 4 + jj) * 128 + 2 * lane) * 2);
                f16x2 m0 = __builtin_bit_cast(f16x2, mpu.x);
                f16x2 m1 = __builtin_bit_cast(f16x2, mpu.y);
                f16x2 wp = __builtin_bit_cast(f16x2, wp_[jj]);
                f16x2 q0 = __builtin_bit_cast(f16x2, q0p[jj]);
                f16x2 q1 = __builtin_bit_cast(f16x2, q1p[jj]);
                acc00 = dot2acc(relu2(q0 + m0), wp, acc00);
                acc01 = dot2acc(relu2(q0 + m1), wp, acc01);
                acc10 = dot2acc(relu2(q1 + m0), wp, acc10);
                acc11 = dot2acc(relu2(q1 + m1), wp, acc11);
            }
        }
    }

    const float r00 = 1.f / (1.f + __expf(-(acc00 + b2v)));
    const float r01 = 1.f / (1.f + __expf(-(acc01 + b2v)));
    const float r10 = 1.f / (1.f + __expf(-(acc10 + b2v)));
    const float r11 = 1.f / (1.f + __expf(-(acc11 + b2v)));
    float2 v0 = { r00, r01 }, v1 = { r10, r11 };
    *(float2*)(rel + (rowbase + 2 * sg) * 128 + 2 * lane)     = v0;
    *(float2*)(rel + (rowbase + 2 * sg + 1) * 128 + 2 * lane) = v1;
}

// ---------------------------------------------------------------------------
// attn_kernel: scores = (Q@K^T)/32 * rel -> softmax -> attn_w, P@V + bv.
// grid 128 = (b, 16-s tile). 256 thr = 4 waves.
// QK: wave w does k-quarter, partials reduced in LDS. PV: wave w does d-quarter.
// ---------------------------------------------------------------------------
__global__ __launch_bounds__(256) void attn_kernel(
    const f16* __restrict__ Q,       // [2048][1024]
    const f16* __restrict__ K,       // [256][1024]
    const f16* __restrict__ Vt,      // [1024][256]  (V^T, cols = b*128+m)
    const float* __restrict__ rel,   // [2048][128]
    const float* __restrict__ bv,    // [1024]
    f16* __restrict__ attn_out,      // [2048][1024]
    float* __restrict__ attn_w)      // [2048][128]
{
    __shared__ float sc[4 * 16 * 128];   // 32 KB partial scores
    __shared__ f16 P[16 * 136];          // padded P tile

    const int tid = threadIdx.x, w = tid >> 6, lane = tid & 63;
    const int b = blockIdx.x >> 6, st = blockIdx.x & 63;
    const size_t rowbase = (size_t)b * SEQ + st * 16;
    const int l15 = lane & 15, l4 = lane >> 4;

    // ---- QK^T partials over k-quarter [w*256, w*256+256) ----
    f32x4 aq[8];
    #pragma unroll
    for (int n = 0; n < 8; ++n) aq[n] = (f32x4){0.f, 0.f, 0.f, 0.f};
    #pragma unroll
    for (int k4 = 0; k4 < 8; ++k4) {
        const int k0 = w * 256 + k4 * 32 + l4 * 8;
        f16x8 af = *(const f16x8*)(Q + (rowbase + l15) * 1024 + k0);
        #pragma unroll
        for (int n = 0; n < 8; ++n) {
            f16x8 bf = *(const f16x8*)(K + (size_t)(b * 128 + n * 16 + l15) * 1024 + k0);
            aq[n] = __builtin_amdgcn_mfma_f32_16x16x32_f16(af, bf, aq[n], 0, 0, 0);
        }
    }
    #pragma unroll
    for (int n = 0; n < 8; ++n)
        #pragma unroll
        for (int j = 0; j < 4; ++j)
            sc[(w * 16 + l4 * 4 + j) * 128 + n * 16 + l15] = aq[n][j];
    __syncthreads();

    // ---- reduce partials, *rel/32, softmax, write attn_w + P(f16) ----
    {
        const int r = tid >> 4, seg = tid & 15;
        float4 xa = {0.f,0.f,0.f,0.f}, xb = {0.f,0.f,0.f,0.f};
        #pragma unroll
        for (int ww = 0; ww < 4; ++ww) {
            float4 pa = *(const float4*)(sc + ww * 2048 + r * 128 + seg * 8);
            float4 pb = *(const float4*)(sc + ww * 2048 + r * 128 + seg * 8 + 4);
            xa.x += pa.x; xa.y += pa.y; xa.z += pa.z; xa.w += pa.w;
            xb.x += pb.x; xb.y += pb.y; xb.z += pb.z; xb.w += pb.w;
        }
        float4 ra = *(const float4*)(rel + (rowbase + r) * 128 + seg * 8);
        float4 rb = *(const float4*)(rel + (rowbase + r) * 128 + seg * 8 + 4);
        float x[8];
        x[0] = xa.x * 0.03125f * ra.x; x[1] = xa.y * 0.03125f * ra.y;
        x[2] = xa.z * 0.03125f * ra.z; x[3] = xa.w * 0.03125f * ra.w;
        x[4] = xb.x * 0.03125f * rb.x; x[5] = xb.y * 0.03125f * rb.y;
        x[6] = xb.z * 0.03125f * rb.z; x[7] = xb.w * 0.03125f * rb.w;
        float mx = x[0];
        #pragma unroll
        for (int c = 1; c < 8; ++c) mx = fmaxf(mx, x[c]);
        #pragma unroll
        for (int d = 1; d < 16; d <<= 1) mx = fmaxf(mx, __shfl_xor(mx, d));
        float ss = 0.f;
        #pragma unroll
        for (int c = 0; c < 8; ++c) { x[c] = __expf(x[c] - mx); ss += x[c]; }
        #pragma unroll
        for (int d = 1; d < 16; d <<= 1) ss += __shfl_xor(ss, d);
        const float inv = 1.f / ss;
        #pragma unroll
        for (int c = 0; c < 8; ++c) x[c] *= inv;
        float4 o0 = { x[0], x[1], x[2], x[3] }, o1 = { x[4], x[5], x[6], x[7] };
        *(float4*)(attn_w + (rowbase + r) * 128 + seg * 8)     = o0;
        *(float4*)(attn_w + (rowbase + r) * 128 + seg * 8 + 4) = o1;
        f16x8 ph = { (f16)x[0], (f16)x[1], (f16)x[2], (f16)x[3],
                     (f16)x[4], (f16)x[5], (f16)x[6], (f16)x[7] };
        *(f16x8*)(P + r * 136 + seg * 8) = ph;
    }
    __syncthreads();

    // ---- PV over d-quarter [w*256, w*256+256) ----
    f16x8 pa[4];
    #pragma unroll
    for (int k = 0; k < 4; ++k)
        pa[k] = *(const f16x8*)(P + l15 * 136 + k * 32 + l4 * 8);
    #pragma unroll
    for (int n2 = 0; n2 < 16; ++n2) {
        f32x4 ac = (f32x4){0.f, 0.f, 0.f, 0.f};
        const int d0 = w * 256 + n2 * 16;
        #pragma unroll
        for (int k = 0; k < 4; ++k) {
            f16x8 bf = *(const f16x8*)(Vt + (size_t)(d0 + l15) * 256 + b * 128 + k * 32 + l4 * 8);
            ac = __builtin_amdgcn_mfma_f32_16x16x32_f16(pa[k], bf, ac, 0, 0, 0);
        }
        const float bvv = bv[d0 + l15];
        #pragma unroll
        for (int j = 0; j < 4; ++j)
            attn_out[(rowbase + l4 * 4 + j) * 1024 + d0 + l15] = (f16)(ac[j] + bvv);
    }
}

// ---------------------------------------------------------------------------
extern "C" void kernel_launch(void* const* d_in, const int* in_sizes, int n_in,
                              void* d_out, int out_size, void* d_ws, size_t ws_size,
                              hipStream_t stream)
{
    const float* hs  = (const float*)d_in[0];
    const float* mem = (const float*)d_in[1];
    const float* Wq  = (const float*)d_in[2];
    const float* bq  = (const float*)d_in[3];
    const float* Wk  = (const float*)d_in[4];
    const float* bk  = (const float*)d_in[5];
    const float* Wv  = (const float*)d_in[6];
    const float* bv  = (const float*)d_in[7];
    const float* Wo  = (const float*)d_in[8];
    const float* bo  = (const float*)d_in[9];
    const float* W1  = (const float*)d_in[10];  // (1536,512)
    const float* b1  = (const float*)d_in[11];
    const float* W2  = (const float*)d_in[12];
    const float* b2  = (const float*)d_in[13];

    float* out   = (float*)d_out;                       // (2,1024,1024)
    float* attnw = out + (size_t)BATCH * SEQ * DM;      // (2,1024,128)

    // workspace layout (f16 unless noted); total ~20.3 MB
    char* w = (char*)d_ws;
    f16* mem_f16  = (f16*)w;  w += (size_t)BATCH * MMEM * MEMD * 2;   // 0.25 MB
    f16* Wq_t     = (f16*)w;  w += (size_t)DM * DM * 2;               // 2 MB
    f16* Wk_t     = (f16*)w;  w += (size_t)DM * MEMD * 2;             // 1 MB
    f16* Wv_t     = (f16*)w;  w += (size_t)DM * MEMD * 2;             // 1 MB
    f16* Wo_t     = (f16*)w;  w += (size_t)DM * DM * 2;               // 2 MB
    f16* W1q_t    = (f16*)w;  w += (size_t)RELH * DM * 2;             // 1 MB
    f16* W1m_t    = (f16*)w;  w += (size_t)RELH * MEMD * 2;           // 0.5 MB
    f16* queries  = (f16*)w;  w += (size_t)BATCH * SEQ * DM * 2;      // 4 MB
    f16* q_part   = (f16*)w;  w += (size_t)BATCH * SEQ * RELH * 2;    // 2 MB
    f16* keys     = (f16*)w;  w += (size_t)BATCH * MMEM * DM * 2;     // 0.5 MB
    f16* Vt       = (f16*)w;  w += (size_t)DM * BATCH * MMEM * 2;     // 0.5 MB
    f16* m_part   = (f16*)w;  w += (size_t)BATCH * MMEM * RELH * 2;   // 0.25 MB
    f16* mpt      = (f16*)w;  w += (size_t)BATCH * MMEM * RELH * 2;   // 0.25 MB
    float* rel    = (float*)w; w += (size_t)BATCH * SEQ * MMEM * 4;   // 1 MB
    f16* hsA      = (f16*)w;  w += (size_t)BATCH * SEQ * DM * 2;      // 4 MB (hs_f16, then attn_out)

    f16* hs_f16   = hsA;   // consumed by queries-GEMM, then reused
    f16* attn_out = hsA;

    dim3 blk(256);

    // casts + weight transposes
    cast_f32_f16<<<dim3((BATCH * SEQ * DM) / 2048), blk, 0, stream>>>(
        hs, hs_f16, (BATCH * SEQ * DM) / 8);
    cast_f32_f16<<<dim3((BATCH * MMEM * MEMD) / 2048), blk, 0, stream>>>(
        mem, mem_f16, (BATCH * MMEM * MEMD) / 8);
    transpose_cast<<<dim3(16, 16), blk, 0, stream>>>(Wq, Wq_t, DM, DM);
    transpose_cast<<<dim3(16, 8),  blk, 0, stream>>>(Wk, Wk_t, MEMD, DM);
    transpose_cast<<<dim3(16, 8),  blk, 0, stream>>>(Wv, Wv_t, MEMD, DM);
    transpose_cast<<<dim3(16, 16), blk, 0, stream>>>(Wo, Wo_t, DM, DM);
    transpose_cast<<<dim3(8, 16),  blk, 0, stream>>>(W1, W1q_t, DM, RELH);
    transpose_cast<<<dim3(8, 8),   blk, 0, stream>>>(W1 + (size_t)DM * RELH, W1m_t, MEMD, RELH);

    // queries = hs @ Wq + bq  (f16)
    gemm_h<<<dim3(DM / 128, (BATCH * SEQ) / 64), blk, 0, stream>>>(
        hs_f16, Wq_t, bq, nullptr, queries, DM, DM);
    // keys = mem @ Wk + bk  (f16)
    gemm_h<<<dim3(DM / 128, (BATCH * MMEM) / 64), blk, 0, stream>>>(
        mem_f16, Wk_t, bk, nullptr, keys, DM, MEMD);
    // Vt = Wv^T @ mem^T  (f16, [1024][256], bias bv applied in attn epilogue)
    gemm_h<<<dim3((BATCH * MMEM) / 128, DM / 64), blk, 0, stream>>>(
        Wv_t, mem_f16, nullptr, nullptr, Vt, BATCH * MMEM, MEMD);
    // m_part = mem @ W1m + b1  (f16; b1 folded here)
    gemm_h<<<dim3(RELH / 128, (BATCH * MMEM) / 64), blk, 0, stream>>>(
        mem_f16, W1m_t, b1, nullptr, m_part, RELH, MEMD);
    // q_part = queries @ W1q  (f16)
    gemm_h<<<dim3(RELH / 128, (BATCH * SEQ) / 64), blk, 0, stream>>>(
        queries, W1q_t, nullptr, nullptr, q_part, RELH, DM);

    // m_part transpose to [b][h2][m][2]
    mpt_kernel<<<dim3(8), blk, 0, stream>>>(m_part, mpt);

    // relevance
    relevance_kernel<<<dim3(256), blk, 0, stream>>>(q_part, mpt, W2, b2, rel);

    // scores/softmax/PV
    attn_kernel<<<dim3(128), blk, 0, stream>>>(
        queries, keys, Vt, rel, bv, attn_out, attnw);

    // out = attn_out @ Wo + bo  (f32)
    gemm_h<<<dim3(DM / 128, (BATCH * SEQ) / 64), blk, 0, stream>>>(
        attn_out, Wo_t, bo, out, nullptr, DM, DM);
}

// Round 5
// 122.318 us; speedup vs baseline: 3.0568x; 1.1227x over previous
//
#include <hip/hip_runtime.h>
#include <math.h>

// Problem constants (fixed by reference)
#define BATCH 2
#define SEQ   1024
#define DM    1024   // D_MODEL
#define MMEM  128    // memory slots
#define MEMD  512    // MEM_DIM
#define RELH  512    // REL_HID
#define KVLD  2560   // ld of combined [keys|values|m_part] output

typedef _Float16 f16;
typedef __attribute__((ext_vector_type(2))) _Float16 f16x2;
typedef __attribute__((ext_vector_type(4))) _Float16 f16x4;
typedef __attribute__((ext_vector_type(8))) _Float16 f16x8;
typedef __attribute__((ext_vector_type(4))) float    f32x4;

__device__ inline float dot2acc(f16x2 a, f16x2 b, float c) {
#if __has_builtin(__builtin_amdgcn_fdot2)
    return __builtin_amdgcn_fdot2(a, b, c, false);
#else
    return c + (float)a[0] * (float)b[0] + (float)a[1] * (float)b[1];
#endif
}
__device__ inline f16x2 relu2(f16x2 a) {
    f16x2 z = { (_Float16)0.0f, (_Float16)0.0f };
#if __has_builtin(__builtin_elementwise_max)
    return __builtin_elementwise_max(a, z);
#else
    f16x2 r;
    r[0] = a[0] > z[0] ? a[0] : z[0];
    r[1] = a[1] > z[1] ? a[1] : z[1];
    return r;
#endif
}

// async global->LDS, 16B per lane (wave-uniform LDS base + lane*16)
__device__ inline void llds16(const void* gp, void* lp) {
    __builtin_amdgcn_global_load_lds(
        (const __attribute__((address_space(1))) void*)gp,
        (__attribute__((address_space(3))) void*)lp,
        16, 0, 0);
}

// ---------------------------------------------------------------------------
// prep: all input casts + weight transposes + bias concat in ONE launch.
// grid 2049 x 256.
//   [0,1024)      hs f32->f16
//   [1024,1088)   mem f32->f16
//   [1088,1344)   Wq^T  (1024x1024) -> Wq_t
//   [1344,1472)   Wk^T  (512x1024)  -> btcomb rows [0,1024)
//   [1472,1600)   Wv^T  (512x1024)  -> btcomb rows [1024,2048)
//   [1600,1856)   Wo^T  (1024x1024) -> Wo_t
//   [1856,1984)   W1q^T (1024x512)  -> W1q_t
//   [1984,2048)   W1m^T (512x512)   -> btcomb rows [2048,2560)
//   2048          bcomb = [bk|bv|b1]
// ---------------------------------------------------------------------------
__device__ inline void tr_tile(float (*t)[65], const float* in, f16* out,
                               int R, int C, int tile) {
    const int tid = threadIdx.x;
    const int ctiles = C >> 6;
    const int r0 = (tile / ctiles) * 64, c0 = (tile % ctiles) * 64;
    #pragma unroll
    for (int i = 0; i < 16; ++i) {
        int idx = tid + 256 * i;
        int r = idx >> 6, c = idx & 63;
        t[c][r] = in[(size_t)(r0 + r) * C + c0 + c];
    }
    __syncthreads();
    #pragma unroll
    for (int i = 0; i < 16; ++i) {
        int idx = tid + 256 * i;
        int ro = idx >> 6, co = idx & 63;
        out[(size_t)(c0 + ro) * R + r0 + co] = (f16)t[ro][co];
    }
}

__global__ __launch_bounds__(256) void prep(
    const float* __restrict__ hs, const float* __restrict__ mem,
    const float* __restrict__ Wq, const float* __restrict__ Wk,
    const float* __restrict__ Wv, const float* __restrict__ Wo,
    const float* __restrict__ W1,
    const float* __restrict__ bk, const float* __restrict__ bv,
    const float* __restrict__ b1,
    f16* __restrict__ hs_f16, f16* __restrict__ mem_f16,
    f16* __restrict__ Wq_t, f16* __restrict__ btcomb,
    f16* __restrict__ Wo_t, f16* __restrict__ W1q_t,
    float* __restrict__ bcomb)
{
    __shared__ float t[64][65];
    const int bid = blockIdx.x, tid = threadIdx.x;

    if (bid < 1024) {                       // hs cast
        int i = bid * 256 + tid;
        const float4* p = (const float4*)hs + (size_t)i * 2;
        float4 a = p[0], b = p[1];
        f16x8 v = { (f16)a.x, (f16)a.y, (f16)a.z, (f16)a.w,
                    (f16)b.x, (f16)b.y, (f16)b.z, (f16)b.w };
        *(f16x8*)(hs_f16 + (size_t)i * 8) = v;
    } else if (bid < 1088) {                // mem cast
        int i = (bid - 1024) * 256 + tid;
        const float4* p = (const float4*)mem + (size_t)i * 2;
        float4 a = p[0], b = p[1];
        f16x8 v = { (f16)a.x, (f16)a.y, (f16)a.z, (f16)a.w,
                    (f16)b.x, (f16)b.y, (f16)b.z, (f16)b.w };
        *(f16x8*)(mem_f16 + (size_t)i * 8) = v;
    } else if (bid < 1344) {
        tr_tile(t, Wq, Wq_t, 1024, 1024, bid - 1088);
    } else if (bid < 1472) {
        tr_tile(t, Wk, btcomb, 512, 1024, bid - 1344);
    } else if (bid < 1600) {
        tr_tile(t, Wv, btcomb + (size_t)1024 * 512, 512, 1024, bid - 1472);
    } else if (bid < 1856) {
        tr_tile(t, Wo, Wo_t, 1024, 1024, bid - 1600);
    } else if (bid < 1984) {
        tr_tile(t, W1, W1q_t, 1024, 512, bid - 1856);
    } else if (bid < 2048) {
        tr_tile(t, W1 + (size_t)1024 * 512, btcomb + (size_t)2048 * 512,
                512, 512, bid - 1984);
    } else {                                // bias concat
        #pragma unroll
        for (int j = 0; j < 10; ++j) {
            int g = tid + 256 * j;
            float v = (g < 1024) ? bk[g] : (g < 2048) ? bv[g - 1024] : b1[g - 2048];
            bcomb[g] = v;
        }
    }
}

// ---------------------------------------------------------------------------
// fp16 MFMA GEMM, global_load_lds staging (swizzled source, linear LDS dest,
// XOR-swizzled fragment reads). C = A @ Bt^T + bias.
//   A : [M][K] f16, Bt : [N][K] f16. BM=64, BN=128, BK=64, 256 thr = 4 waves.
// Double-buffered LDS (48 KB), ONE barrier per K-tile.
// grid (N/128, M/64). Outputs f32 C and/or f16 C2 with row stride ldc.
// ---------------------------------------------------------------------------
__global__ __launch_bounds__(256) void gemm_h(
    const f16* __restrict__ A, const f16* __restrict__ Bt,
    const float* __restrict__ bias, float* __restrict__ C,
    f16* __restrict__ C2, int N, int K, int ldc)
{
    __shared__ f16 Al[2][64 * 64];    // 8 KB per buffer, linear [row][64k]
    __shared__ f16 Bl[2][128 * 64];   // 16 KB per buffer

    const int tid = threadIdx.x, lane = tid & 63, wid = tid >> 6;
    const size_t row0 = (size_t)blockIdx.y * 64;
    const size_t col0 = (size_t)blockIdx.x * 128;

    const int lrow = lane >> 3;           // row within 8-row chunk
    const int lcs  = (lane & 7) ^ lrow;   // inverse-swizzled source 16B-chunk
    const int r15 = lane & 15, l4 = lane >> 4;

    f32x4 acc[4][2];
    #pragma unroll
    for (int m = 0; m < 4; ++m)
        #pragma unroll
        for (int n = 0; n < 2; ++n) acc[m][n] = (f32x4){0.f, 0.f, 0.f, 0.f};

#define STAGE(buf, kt) do {                                                   \
    const f16* Ab_ = A + row0 * K + (size_t)(kt) * 64;                        \
    const f16* Bb_ = Bt + col0 * K + (size_t)(kt) * 64;                       \
    _Pragma("unroll")                                                         \
    for (int j_ = 0; j_ < 2; ++j_) {                                          \
        const int c_ = wid * 2 + j_;                                          \
        llds16(Ab_ + (size_t)(c_ * 8 + lrow) * K + lcs * 8,                   \
               &Al[buf][c_ * 512]);                                           \
    }                                                                         \
    _Pragma("unroll")                                                         \
    for (int j_ = 0; j_ < 4; ++j_) {                                          \
        const int c_ = wid * 4 + j_;                                          \
        llds16(Bb_ + (size_t)(c_ * 8 + lrow) * K + lcs * 8,                   \
               &Bl[buf][c_ * 512]);                                           \
    }                                                                         \
} while (0)

    STAGE(0, 0);
    __syncthreads();                     // drains vmcnt: buffer 0 ready

    const int nk = K >> 6;
    int cur = 0;
    for (int kt = 0; kt < nk; ++kt) {
        if (kt + 1 < nk) STAGE(cur ^ 1, kt + 1);   // async prefetch
        #pragma unroll
        for (int kk = 0; kk < 2; ++kk) {
            f16x8 af[4], bfr[2];
            #pragma unroll
            for (int m = 0; m < 4; ++m) {
                const int rowA = m * 16 + r15;
                af[m] = *(const f16x8*)(
                    &Al[cur][rowA * 64 + (((kk * 4 + l4) ^ (r15 & 7)) * 8)]);
            }
            #pragma unroll
            for (int n = 0; n < 2; ++n) {
                const int rowB = wid * 32 + n * 16 + r15;
                bfr[n] = *(const f16x8*)(
                    &Bl[cur][rowB * 64 + (((kk * 4 + l4) ^ (r15 & 7)) * 8)]);
            }
            #pragma unroll
            for (int m = 0; m < 4; ++m)
                #pragma unroll
                for (int n = 0; n < 2; ++n)
                    acc[m][n] = __builtin_amdgcn_mfma_f32_16x16x32_f16(
                        af[m], bfr[n], acc[m][n], 0, 0, 0);
        }
        __syncthreads();   // cur consumed by all; cur^1 staging complete
        cur ^= 1;
    }
#undef STAGE

    // C/D layout: col = lane&15, row = (lane>>4)*4 + j
    const int cr = lane >> 4, cc = lane & 15;
    #pragma unroll
    for (int n = 0; n < 2; ++n) {
        const size_t col = col0 + wid * 32 + n * 16 + cc;
        const float bvv = bias ? bias[col] : 0.f;
        #pragma unroll
        for (int m = 0; m < 4; ++m) {
            #pragma unroll
            for (int j = 0; j < 4; ++j) {
                const size_t row = row0 + m * 16 + cr * 4 + j;
                const float v = acc[m][n][j] + bvv;
                if (C)  C[row * ldc + col] = v;
                if (C2) C2[row * ldc + col] = (f16)v;
            }
        }
    }
}

// ---------------------------------------------------------------------------
// posttrans: Vt = values^T (from kvm cols [1024,2048)) and mpt from m_part
// (kvm cols [2048,2560)). grid 72 x 256.
// ---------------------------------------------------------------------------
__global__ __launch_bounds__(256) void posttrans(
    const f16* __restrict__ kvm, f16* __restrict__ Vt, f16* __restrict__ mpt)
{
    __shared__ f16 tf[64][72];
    __shared__ f16 t2[128][136];
    const int bid = blockIdx.x, tid = threadIdx.x;

    if (bid < 64) {
        // transpose values [256][1024] (ld KVLD) -> Vt [1024][256]
        const f16* vals = kvm + 1024;
        const int r0 = (bid / 16) * 64, c0 = (bid % 16) * 64;
        #pragma unroll
        for (int kq = 0; kq < 2; ++kq) {
            int idx = tid + 256 * kq;
            int r = idx >> 3, ch = idx & 7;
            *(f16x8*)(&tf[r][ch * 8]) =
                *(const f16x8*)(vals + (size_t)(r0 + r) * KVLD + c0 + ch * 8);
        }
        __syncthreads();
        #pragma unroll
        for (int kq = 0; kq < 2; ++kq) {
            int idx = tid + 256 * kq;
            int oc = idx & 63, og = idx >> 6;
            f16x8 v;
            #pragma unroll
            for (int j = 0; j < 8; ++j) v[j] = tf[og * 8 + j][oc];
            *(f16x8*)(Vt + (size_t)(c0 + oc) * 256 + r0 + og * 8) = v;
        }
    } else {
        // mpt: m_part [b*128+m][512] (ld KVLD, offset 2048) -> [b][h2][m][2]
        const f16* mpart = kvm + 2048;
        const int mb = bid - 64, b = mb >> 2, hc = mb & 3;
        #pragma unroll
        for (int k = 0; k < 8; ++k) {
            int idx = tid + 256 * k;
            int m = idx >> 4, hs_ = idx & 15;
            *(f16x8*)(&t2[m][hs_ * 8]) =
                *(const f16x8*)(mpart + (size_t)(b * 128 + m) * KVLD + hc * 128 + hs_ * 8);
        }
        __syncthreads();
        #pragma unroll
        for (int k = 0; k < 32; ++k) {
            int idx = tid + 256 * k;
            int h2l = idx >> 7, m = idx & 127;
            f16x2 v = { t2[m][h2l * 2], t2[m][h2l * 2 + 1] };
            *(f16x2*)(mpt + ((size_t)b * 256 + hc * 64 + h2l) * 256 + m * 2) = v;
        }
    }
}

// ---------------------------------------------------------------------------
// relevance_kernel: rel[b,s,m] = sigmoid(sum_h relu(qp[s,h]+mp[m,h])*w2[h]+b2)
// (b1 folded into m_part via GEMM bias.) grid 256 x 256.
// ---------------------------------------------------------------------------
__global__ __launch_bounds__(256) void relevance_kernel(
    const f16* __restrict__ q_part,  // [2048][512]
    const f16* __restrict__ mpt,     // [b][256 h2][128 m][2]
    const float* __restrict__ W2,    // [512]
    const float* __restrict__ b2,    // [1]
    float* __restrict__ rel)         // [2048][128]
{
    __shared__ f16 qs[8 * 512];
    __shared__ f16 mps[64 * 256];
    __shared__ f16 w2s[512];

    const int tid = threadIdx.x;
    const int b = blockIdx.x >> 7, st = blockIdx.x & 127;
    const size_t rowbase = (size_t)b * SEQ + st * 8;

    {
        int r = tid >> 5, c = tid & 31;
        const f16* src = q_part + (rowbase + r) * 512 + c * 16;
        *(f16x8*)(qs + r * 512 + c * 16)     = *(const f16x8*)(src);
        *(f16x8*)(qs + r * 512 + c * 16 + 8) = *(const f16x8*)(src + 8);
    }
    if (tid < 128) {
        float4 w4 = *(const float4*)(W2 + tid * 4);
        f16x4 hv = { (f16)w4.x, (f16)w4.y, (f16)w4.z, (f16)w4.w };
        *(f16x4*)(w2s + tid * 4) = hv;
    }
    const float b2v = b2[0];
    const int sg = tid >> 6, lane = tid & 63;

    float acc00 = 0.f, acc01 = 0.f, acc10 = 0.f, acc11 = 0.f;
    const f16* mptb = mpt + (size_t)b * 65536;

    for (int hc = 0; hc < 4; ++hc) {
        __syncthreads();
        {
            const f16x8* src = (const f16x8*)(mptb + hc * 16384);
            f16x8* dst = (f16x8*)mps;
            #pragma unroll
            for (int k = 0; k < 8; ++k) dst[tid + 256 * k] = src[tid + 256 * k];
        }
        __syncthreads();

        #pragma unroll 4
        for (int step = 0; step < 16; ++step) {
            const int habs = hc * 128 + step * 8;
            uint4 q0u = *(const uint4*)(qs + (2 * sg) * 512 + habs);
            uint4 q1u = *(const uint4*)(qs + (2 * sg + 1) * 512 + habs);
            uint4 wu  = *(const uint4*)(w2s + habs);
            const unsigned* q0p = (const unsigned*)&q0u;
            const unsigned* q1p = (const unsigned*)&q1u;
            const unsigned* wp_ = (const unsigned*)&wu;
            #pragma unroll
            for (int jj = 0; jj < 4; ++jj) {
                uint2 mpu = *(const uint2*)(mps + ((step * 4 + jj) * 128 + 2 * lane) * 2);
                f16x2 m0 = __builtin_bit_cast(f16x2, mpu.x);
                f16x2 m1 = __builtin_bit_cast(f16x2, mpu.y);
                f16x2 wp = __builtin_bit_cast(f16x2, wp_[jj]);
                f16x2 q0 = __builtin_bit_cast(f16x2, q0p[jj]);
                f16x2 q1 = __builtin_bit_cast(f16x2, q1p[jj]);
                acc00 = dot2acc(relu2(q0 + m0), wp, acc00);
                acc01 = dot2acc(relu2(q0 + m1), wp, acc01);
                acc10 = dot2acc(relu2(q1 + m0), wp, acc10);
                acc11 = dot2acc(relu2(q1 + m1), wp, acc11);
            }
        }
    }

    const float r00 = 1.f / (1.f + __expf(-(acc00 + b2v)));
    const float r01 = 1.f / (1.f + __expf(-(acc01 + b2v)));
    const float r10 = 1.f / (1.f + __expf(-(acc10 + b2v)));
    const float r11 = 1.f / (1.f + __expf(-(acc11 + b2v)));
    float2 v0 = { r00, r01 }, v1 = { r10, r11 };
    *(float2*)(rel + (rowbase + 2 * sg) * 128 + 2 * lane)     = v0;
    *(float2*)(rel + (rowbase + 2 * sg + 1) * 128 + 2 * lane) = v1;
}

// ---------------------------------------------------------------------------
// attn_kernel: scores = (Q@K^T)/32 * rel -> softmax -> attn_w, P@V.
// (bv folded into values.) K rows live in kvm with ld KVLD.
// grid 128 x 256.
// ---------------------------------------------------------------------------
__global__ __launch_bounds__(256) void attn_kernel(
    const f16* __restrict__ Q,       // [2048][1024]
    const f16* __restrict__ Km,      // [256][KVLD] (cols [0,1024) = keys)
    const f16* __restrict__ Vt,      // [1024][256]
    const float* __restrict__ rel,   // [2048][128]
    f16* __restrict__ attn_out,      // [2048][1024]
    float* __restrict__ attn_w)      // [2048][128]
{
    __shared__ float sc[4 * 16 * 128];
    __shared__ f16 P[16 * 136];

    const int tid = threadIdx.x, w = tid >> 6, lane = tid & 63;
    const int b = blockIdx.x >> 6, st = blockIdx.x & 63;
    const size_t rowbase = (size_t)b * SEQ + st * 16;
    const int l15 = lane & 15, l4 = lane >> 4;

    // ---- QK^T partials over k-quarter ----
    f32x4 aq[8];
    #pragma unroll
    for (int n = 0; n < 8; ++n) aq[n] = (f32x4){0.f, 0.f, 0.f, 0.f};
    #pragma unroll
    for (int k4 = 0; k4 < 8; ++k4) {
        const int k0 = w * 256 + k4 * 32 + l4 * 8;
        f16x8 af = *(const f16x8*)(Q + (rowbase + l15) * 1024 + k0);
        #pragma unroll
        for (int n = 0; n < 8; ++n) {
            f16x8 bf = *(const f16x8*)(Km + (size_t)(b * 128 + n * 16 + l15) * KVLD + k0);
            aq[n] = __builtin_amdgcn_mfma_f32_16x16x32_f16(af, bf, aq[n], 0, 0, 0);
        }
    }
    #pragma unroll
    for (int n = 0; n < 8; ++n)
        #pragma unroll
        for (int j = 0; j < 4; ++j)
            sc[(w * 16 + l4 * 4 + j) * 128 + n * 16 + l15] = aq[n][j];
    __syncthreads();

    // ---- reduce partials, *rel/32, softmax, write attn_w + P(f16) ----
    {
        const int r = tid >> 4, seg = tid & 15;
        float4 xa = {0.f,0.f,0.f,0.f}, xb = {0.f,0.f,0.f,0.f};
        #pragma unroll
        for (int ww = 0; ww < 4; ++ww) {
            float4 pa = *(const float4*)(sc + ww * 2048 + r * 128 + seg * 8);
            float4 pb = *(const float4*)(sc + ww * 2048 + r * 128 + seg * 8 + 4);
            xa.x += pa.x; xa.y += pa.y; xa.z += pa.z; xa.w += pa.w;
            xb.x += pb.x; xb.y += pb.y; xb.z += pb.z; xb.w += pb.w;
        }
        float4 ra = *(const float4*)(rel + (rowbase + r) * 128 + seg * 8);
        float4 rb = *(const float4*)(rel + (rowbase + r) * 128 + seg * 8 + 4);
        float x[8];
        x[0] = xa.x * 0.03125f * ra.x; x[1] = xa.y * 0.03125f * ra.y;
        x[2] = xa.z * 0.03125f * ra.z; x[3] = xa.w * 0.03125f * ra.w;
        x[4] = xb.x * 0.03125f * rb.x; x[5] = xb.y * 0.03125f * rb.y;
        x[6] = xb.z * 0.03125f * rb.z; x[7] = xb.w * 0.03125f * rb.w;
        float mx = x[0];
        #pragma unroll
        for (int c = 1; c < 8; ++c) mx = fmaxf(mx, x[c]);
        #pragma unroll
        for (int d = 1; d < 16; d <<= 1) mx = fmaxf(mx, __shfl_xor(mx, d));
        float ss = 0.f;
        #pragma unroll
        for (int c = 0; c < 8; ++c) { x[c] = __expf(x[c] - mx); ss += x[c]; }
        #pragma unroll
        for (int d = 1; d < 16; d <<= 1) ss += __shfl_xor(ss, d);
        const float inv = 1.f / ss;
        #pragma unroll
        for (int c = 0; c < 8; ++c) x[c] *= inv;
        float4 o0 = { x[0], x[1], x[2], x[3] }, o1 = { x[4], x[5], x[6], x[7] };
        *(float4*)(attn_w + (rowbase + r) * 128 + seg * 8)     = o0;
        *(float4*)(attn_w + (rowbase + r) * 128 + seg * 8 + 4) = o1;
        f16x8 ph = { (f16)x[0], (f16)x[1], (f16)x[2], (f16)x[3],
                     (f16)x[4], (f16)x[5], (f16)x[6], (f16)x[7] };
        *(f16x8*)(P + r * 136 + seg * 8) = ph;
    }
    __syncthreads();

    // ---- PV over d-quarter (bv already folded into V) ----
    f16x8 pa[4];
    #pragma unroll
    for (int k = 0; k < 4; ++k)
        pa[k] = *(const f16x8*)(P + l15 * 136 + k * 32 + l4 * 8);
    #pragma unroll
    for (int n2 = 0; n2 < 16; ++n2) {
        f32x4 ac = (f32x4){0.f, 0.f, 0.f, 0.f};
        const int d0 = w * 256 + n2 * 16;
        #pragma unroll
        for (int k = 0; k < 4; ++k) {
            f16x8 bf = *(const f16x8*)(Vt + (size_t)(d0 + l15) * 256 + b * 128 + k * 32 + l4 * 8);
            ac = __builtin_amdgcn_mfma_f32_16x16x32_f16(pa[k], bf, ac, 0, 0, 0);
        }
        #pragma unroll
        for (int j = 0; j < 4; ++j)
            attn_out[(rowbase + l4 * 4 + j) * 1024 + d0 + l15] = (f16)ac[j];
    }
}

// ---------------------------------------------------------------------------
extern "C" void kernel_launch(void* const* d_in, const int* in_sizes, int n_in,
                              void* d_out, int out_size, void* d_ws, size_t ws_size,
                              hipStream_t stream)
{
    const float* hs  = (const float*)d_in[0];
    const float* mem = (const float*)d_in[1];
    const float* Wq  = (const float*)d_in[2];
    const float* bq  = (const float*)d_in[3];
    const float* Wk  = (const float*)d_in[4];
    const float* bk  = (const float*)d_in[5];
    const float* Wv  = (const float*)d_in[6];
    const float* bv  = (const float*)d_in[7];
    const float* Wo  = (const float*)d_in[8];
    const float* bo  = (const float*)d_in[9];
    const float* W1  = (const float*)d_in[10];  // (1536,512)
    const float* b1  = (const float*)d_in[11];
    const float* W2  = (const float*)d_in[12];
    const float* b2  = (const float*)d_in[13];

    float* out   = (float*)d_out;                       // (2,1024,1024)
    float* attnw = out + (size_t)BATCH * SEQ * DM;      // (2,1024,128)

    // workspace layout (all 16B-aligned; ~21 MB total)
    char* w = (char*)d_ws;
    f16* hsA      = (f16*)w;  w += (size_t)BATCH * SEQ * DM * 2;      // 4 MB (hs_f16 -> attn_out)
    f16* mem_f16  = (f16*)w;  w += (size_t)BATCH * MMEM * MEMD * 2;   // 0.25 MB
    f16* Wq_t     = (f16*)w;  w += (size_t)DM * DM * 2;               // 2 MB
    f16* btcomb   = (f16*)w;  w += (size_t)KVLD * MEMD * 2;           // 2.5 MB
    f16* Wo_t     = (f16*)w;  w += (size_t)DM * DM * 2;               // 2 MB
    f16* W1q_t    = (f16*)w;  w += (size_t)RELH * DM * 2;             // 1 MB
    f16* queries  = (f16*)w;  w += (size_t)BATCH * SEQ * DM * 2;      // 4 MB
    f16* q_part   = (f16*)w;  w += (size_t)BATCH * SEQ * RELH * 2;    // 2 MB
    f16* kvm      = (f16*)w;  w += (size_t)BATCH * MMEM * KVLD * 2;   // 1.25 MB
    f16* Vt       = (f16*)w;  w += (size_t)DM * BATCH * MMEM * 2;     // 0.5 MB
    f16* mpt      = (f16*)w;  w += (size_t)BATCH * MMEM * RELH * 2;   // 0.25 MB
    float* rel    = (float*)w; w += (size_t)BATCH * SEQ * MMEM * 4;   // 1 MB
    float* bcomb  = (float*)w; w += (size_t)KVLD * 4;                 // 10 KB

    f16* hs_f16   = hsA;   // consumed by queries-GEMM, then buffer reused
    f16* attn_out = hsA;

    dim3 blk(256);

    // 1. all casts + transposes + bias concat
    prep<<<dim3(2049), blk, 0, stream>>>(
        hs, mem, Wq, Wk, Wv, Wo, W1, bk, bv, b1,
        hs_f16, mem_f16, Wq_t, btcomb, Wo_t, W1q_t, bcomb);

    // 2. queries = hs @ Wq + bq  (f16)
    gemm_h<<<dim3(DM / 128, (BATCH * SEQ) / 64), blk, 0, stream>>>(
        hs_f16, Wq_t, bq, nullptr, queries, DM, DM, DM);

    // 3. [keys|values+bv|m_part+b1] = mem @ [Wk|Wv|W1m] + bcomb  (f16)
    gemm_h<<<dim3(KVLD / 128, (BATCH * MMEM) / 64), blk, 0, stream>>>(
        mem_f16, btcomb, bcomb, nullptr, kvm, KVLD, MEMD, KVLD);

    // 4. Vt + mpt
    posttrans<<<dim3(72), blk, 0, stream>>>(kvm, Vt, mpt);

    // 5. q_part = queries @ W1q  (f16)
    gemm_h<<<dim3(RELH / 128, (BATCH * SEQ) / 64), blk, 0, stream>>>(
        queries, W1q_t, nullptr, nullptr, q_part, RELH, DM, RELH);

    // 6. relevance
    relevance_kernel<<<dim3(256), blk, 0, stream>>>(q_part, mpt, W2, b2, rel);

    // 7. scores/softmax/PV
    attn_kernel<<<dim3(128), blk, 0, stream>>>(
        queries, kvm, Vt, rel, attn_out, attnw);

    // 8. out = attn_out @ Wo + bo  (f32)
    gemm_h<<<dim3(DM / 128, (BATCH * SEQ) / 64), blk, 0, stream>>>(
        attn_out, Wo_t, bo, out, nullptr, DM, DM, DM);
}

// Round 6
// 102.559 us; speedup vs baseline: 3.6457x; 1.1927x over previous
//
#include <hip/hip_runtime.h>
#include <math.h>

// Problem constants (fixed by reference)
#define BATCH 2
#define SEQ   1024
#define DM    1024   // D_MODEL
#define MMEM  128    // memory slots
#define MEMD  512    // MEM_DIM
#define RELH  512    // REL_HID
#define KVLD  2560   // ld of combined [keys|values|m_part]
#define QLD   1536   // ld of combined [queries|q_part]

typedef _Float16 f16;
typedef __attribute__((ext_vector_type(2))) _Float16 f16x2;
typedef __attribute__((ext_vector_type(4))) _Float16 f16x4;
typedef __attribute__((ext_vector_type(8))) _Float16 f16x8;
typedef __attribute__((ext_vector_type(4))) float    f32x4;

__device__ inline float dot2acc(f16x2 a, f16x2 b, float c) {
#if __has_builtin(__builtin_amdgcn_fdot2)
    return __builtin_amdgcn_fdot2(a, b, c, false);
#else
    return c + (float)a[0] * (float)b[0] + (float)a[1] * (float)b[1];
#endif
}
__device__ inline f16x2 relu2(f16x2 a) {
    f16x2 z = { (_Float16)0.0f, (_Float16)0.0f };
#if __has_builtin(__builtin_elementwise_max)
    return __builtin_elementwise_max(a, z);
#else
    f16x2 r;
    r[0] = a[0] > z[0] ? a[0] : z[0];
    r[1] = a[1] > z[1] ? a[1] : z[1];
    return r;
#endif
}

// async global->LDS, 16B per lane (wave-uniform LDS base + lane*16)
__device__ inline void llds16(const void* gp, void* lp) {
    __builtin_amdgcn_global_load_lds(
        (const __attribute__((address_space(1))) void*)gp,
        (__attribute__((address_space(3))) void*)lp,
        16, 0, 0);
}

__device__ inline void cast8(const float* __restrict__ in, f16* __restrict__ out, int i) {
    const float4* p = (const float4*)in + (size_t)i * 2;
    float4 a = p[0], b = p[1];
    f16x8 v = { (f16)a.x, (f16)a.y, (f16)a.z, (f16)a.w,
                (f16)b.x, (f16)b.y, (f16)b.z, (f16)b.w };
    *(f16x8*)(out + (size_t)i * 8) = v;
}

__device__ inline void tr_tile(float (*t)[65], const float* __restrict__ in,
                               f16* __restrict__ out, int R, int C, int tile) {
    const int tid = threadIdx.x;
    const int ctiles = C >> 6;
    const int r0 = (tile / ctiles) * 64, c0 = (tile % ctiles) * 64;
    #pragma unroll
    for (int i = 0; i < 16; ++i) {
        int idx = tid + 256 * i;
        int r = idx >> 6, c = idx & 63;
        t[c][r] = in[(size_t)(r0 + r) * C + c0 + c];
    }
    __syncthreads();
    #pragma unroll
    for (int i = 0; i < 16; ++i) {
        int idx = tid + 256 * i;
        int ro = idx >> 6, co = idx & 63;
        out[(size_t)(c0 + ro) * R + r0 + co] = (f16)t[ro][co];
    }
}

// ---------------------------------------------------------------------------
// L1 prep: all casts + transposes + bias vectors. grid 2561 x 256.
// ---------------------------------------------------------------------------
__global__ __launch_bounds__(256) void prep(
    const float* __restrict__ hs, const float* __restrict__ mem,
    const float* __restrict__ Wq, const float* __restrict__ Wk,
    const float* __restrict__ Wv, const float* __restrict__ Wo,
    const float* __restrict__ W1,
    const float* __restrict__ bq, const float* __restrict__ bk,
    const float* __restrict__ bv, const float* __restrict__ b1,
    f16* __restrict__ hs_f16, f16* __restrict__ mem_f16,
    f16* __restrict__ Wq_f16, f16* __restrict__ btbig,
    f16* __restrict__ btcomb, f16* __restrict__ Wo_t,
    f16* __restrict__ W1q_t, float* __restrict__ bcomb,
    float* __restrict__ bqcomb)
{
    __shared__ float t[64][65];
    const int bid = blockIdx.x, tid = threadIdx.x;

    if (bid < 1024) {                         // hs f32->f16
        cast8(hs, hs_f16, bid * 256 + tid);
    } else if (bid < 1088) {                  // mem f32->f16
        cast8(mem, mem_f16, (bid - 1024) * 256 + tid);
    } else if (bid < 1600) {                  // Wq straight cast (for wcomb Bt)
        cast8(Wq, Wq_f16, (bid - 1088) * 256 + tid);
    } else if (bid < 1856) {                  // Wq^T -> btbig rows [0,1024)
        tr_tile(t, Wq, btbig, 1024, 1024, bid - 1600);
    } else if (bid < 1984) {                  // Wk^T -> btcomb rows [0,1024)
        tr_tile(t, Wk, btcomb, 512, 1024, bid - 1856);
    } else if (bid < 2112) {                  // Wv^T -> btcomb rows [1024,2048)
        tr_tile(t, Wv, btcomb + (size_t)1024 * 512, 512, 1024, bid - 1984);
    } else if (bid < 2368) {                  // Wo^T
        tr_tile(t, Wo, Wo_t, 1024, 1024, bid - 2112);
    } else if (bid < 2496) {                  // W1q^T
        tr_tile(t, W1, W1q_t, 1024, 512, bid - 2368);
    } else if (bid < 2560) {                  // W1m^T -> btcomb rows [2048,2560)
        tr_tile(t, W1 + (size_t)1024 * 512, btcomb + (size_t)2048 * 512,
                512, 512, bid - 2496);
    } else {                                  // bias vectors
        #pragma unroll
        for (int j = 0; j < 10; ++j) {
            int g = tid + 256 * j;
            float v = (g < 1024) ? bk[g] : (g < 2048) ? bv[g - 1024] : b1[g - 2048];
            bcomb[g] = v;
        }
        #pragma unroll
        for (int j = 0; j < 4; ++j) {
            int g = tid + 256 * j;
            bqcomb[g] = bq[g];                // cols [0,1024) of qcat bias
        }
    }
}

// ---------------------------------------------------------------------------
// Shared MFMA GEMM core: C(f32,opt)/C2(f16,opt) = A @ Bt^T + bias.
// BM=64, BN template (64/128), BK=64, 256 thr = 4 waves.
// global_load_lds staging (inverse-swizzled source, linear LDS, XOR frag read),
// double-buffered.
// ---------------------------------------------------------------------------
template<int BN>
__device__ __forceinline__ void gemm_core(
    const f16* __restrict__ A, const f16* __restrict__ Bt,
    const float* __restrict__ bias, float* __restrict__ C,
    f16* __restrict__ C2, int N, int K, int ldc,
    int bx, int by, f16* Al, f16* Bl)
{
    constexpr int NBW = BN / 32;   // B staging llds16 per wave
    constexpr int NF  = BN / 64;   // n-fragments per wave
    const int tid = threadIdx.x, lane = tid & 63, wid = tid >> 6;
    const size_t row0 = (size_t)by * 64;
    const size_t col0 = (size_t)bx * BN;
    const int lrow = lane >> 3;
    const int lcs  = (lane & 7) ^ lrow;
    const int r15 = lane & 15, l4 = lane >> 4;

    f32x4 acc[4][NF];
    #pragma unroll
    for (int m = 0; m < 4; ++m)
        #pragma unroll
        for (int n = 0; n < NF; ++n) acc[m][n] = (f32x4){0.f, 0.f, 0.f, 0.f};

    auto STAGE = [&](int buf, int kt) {
        const f16* Ab = A + row0 * K + (size_t)kt * 64;
        const f16* Bb = Bt + col0 * K + (size_t)kt * 64;
        #pragma unroll
        for (int j = 0; j < 2; ++j) {
            const int c = wid * 2 + j;
            llds16(Ab + (size_t)(c * 8 + lrow) * K + lcs * 8,
                   Al + buf * 4096 + c * 512);
        }
        #pragma unroll
        for (int j = 0; j < NBW; ++j) {
            const int c = wid * NBW + j;
            llds16(Bb + (size_t)(c * 8 + lrow) * K + lcs * 8,
                   Bl + buf * (BN * 64) + c * 512);
        }
    };

    STAGE(0, 0);
    __syncthreads();

    const int nk = K >> 6;
    int cur = 0;
    for (int kt = 0; kt < nk; ++kt) {
        if (kt + 1 < nk) STAGE(cur ^ 1, kt + 1);
        #pragma unroll
        for (int kk = 0; kk < 2; ++kk) {
            f16x8 af[4], bfr[NF];
            #pragma unroll
            for (int m = 0; m < 4; ++m) {
                const int rowA = m * 16 + r15;
                af[m] = *(const f16x8*)(
                    Al + cur * 4096 + rowA * 64 + (((kk * 4 + l4) ^ (r15 & 7)) * 8));
            }
            #pragma unroll
            for (int n = 0; n < NF; ++n) {
                const int rowB = wid * (BN / 4) + n * 16 + r15;
                bfr[n] = *(const f16x8*)(
                    Bl + cur * (BN * 64) + rowB * 64 + (((kk * 4 + l4) ^ (r15 & 7)) * 8));
            }
            #pragma unroll
            for (int m = 0; m < 4; ++m)
                #pragma unroll
                for (int n = 0; n < NF; ++n)
                    acc[m][n] = __builtin_amdgcn_mfma_f32_16x16x32_f16(
                        af[m], bfr[n], acc[m][n], 0, 0, 0);
        }
        __syncthreads();
        cur ^= 1;
    }

    // C/D layout: col = lane&15, row = (lane>>4)*4 + j
    const int cr = l4, cc = r15;
    #pragma unroll
    for (int n = 0; n < NF; ++n) {
        const size_t col = col0 + wid * (BN / 4) + n * 16 + cc;
        const float bvv = bias ? bias[col] : 0.f;
        #pragma unroll
        for (int m = 0; m < 4; ++m) {
            #pragma unroll
            for (int j = 0; j < 4; ++j) {
                const size_t row = row0 + m * 16 + cr * 4 + j;
                const float v = acc[m][n][j] + bvv;
                if (C)  C[row * ldc + col] = v;
                if (C2) C2[row * ldc + col] = (f16)v;
            }
        }
    }
}

// ---------------------------------------------------------------------------
// L2: batched small GEMMs + bias-combine. grid 145 x 256.
//   [0,80)   kvm = mem @ [Wk|Wv|W1m] + [bk|bv|b1]   (N=2560, K=512)
//   [80,144) Wq1_t = W1q_t @ Wq_f16^T               (-> btbig rows [1024,1536))
//   144      bqcomb[1024..1536) = bq @ W1q
// ---------------------------------------------------------------------------
__global__ __launch_bounds__(256) void smallgemms(
    const f16* __restrict__ mem_f16, const f16* __restrict__ btcomb,
    const float* __restrict__ bcomb, f16* __restrict__ kvm,
    const f16* __restrict__ W1q_t, const f16* __restrict__ Wq_f16,
    f16* __restrict__ wq1t, const float* __restrict__ bq,
    float* __restrict__ bqcomb)
{
    __shared__ __align__(16) char smem[49152];
    f16* Al = (f16*)smem;
    f16* Bl = (f16*)(smem + 16384);
    const int bid = blockIdx.x;

    if (bid < 80) {
        gemm_core<128>(mem_f16, btcomb, bcomb, nullptr, kvm,
                       KVLD, MEMD, KVLD, bid % 20, bid / 20, Al, Bl);
    } else if (bid < 144) {
        const int i = bid - 80;
        gemm_core<128>(W1q_t, Wq_f16, nullptr, nullptr, wq1t,
                       DM, DM, DM, i % 8, i / 8, Al, Bl);
    } else {
        float* bqs = (float*)smem;
        const int tid = threadIdx.x;
        #pragma unroll
        for (int j = 0; j < 4; ++j) bqs[tid + 256 * j] = bq[tid + 256 * j];
        __syncthreads();
        #pragma unroll
        for (int rr = 0; rr < 2; ++rr) {
            const int j = tid + rr * 256;
            float acc = 0.f;
            for (int k8 = 0; k8 < 128; ++k8) {
                f16x8 wv = *(const f16x8*)(W1q_t + (size_t)j * 1024 + k8 * 8);
                #pragma unroll
                for (int e = 0; e < 8; ++e) acc += bqs[k8 * 8 + e] * (float)wv[e];
            }
            bqcomb[1024 + j] = acc;
        }
    }
}

// ---------------------------------------------------------------------------
// L3: big GEMM [queries|q_part] = hs @ [Wq|Wq@W1q] + [bq|bq@W1q]
//     + posttrans (Vt, mpt) blocks. grid 456 x 256.
// ---------------------------------------------------------------------------
__global__ __launch_bounds__(256) void biggemm(
    const f16* __restrict__ hs_f16, const f16* __restrict__ btbig,
    const float* __restrict__ bqcomb, f16* __restrict__ qcat,
    const f16* __restrict__ kvm, f16* __restrict__ Vt, f16* __restrict__ mpt)
{
    __shared__ __align__(16) char smem[49152];
    const int bid = blockIdx.x, tid = threadIdx.x;

    if (bid < 384) {
        gemm_core<128>(hs_f16, btbig, bqcomb, nullptr, qcat,
                       QLD, DM, QLD, bid % 12, bid / 12,
                       (f16*)smem, (f16*)(smem + 16384));
        return;
    }
    const int pb = bid - 384;
    if (pb < 64) {
        // transpose values [256][KVLD cols 1024..2048) -> Vt [1024][256]
        f16 (*tf)[72] = (f16(*)[72])smem;
        const f16* vals = kvm + 1024;
        const int r0 = (pb / 16) * 64, c0 = (pb % 16) * 64;
        #pragma unroll
        for (int kq = 0; kq < 2; ++kq) {
            int idx = tid + 256 * kq;
            int r = idx >> 3, ch = idx & 7;
            *(f16x8*)(&tf[r][ch * 8]) =
                *(const f16x8*)(vals + (size_t)(r0 + r) * KVLD + c0 + ch * 8);
        }
        __syncthreads();
        #pragma unroll
        for (int kq = 0; kq < 2; ++kq) {
            int idx = tid + 256 * kq;
            int oc = idx & 63, og = idx >> 6;
            f16x8 v;
            #pragma unroll
            for (int j = 0; j < 8; ++j) v[j] = tf[og * 8 + j][oc];
            *(f16x8*)(Vt + (size_t)(c0 + oc) * 256 + r0 + og * 8) = v;
        }
    } else {
        // mpt: m_part rows (kvm cols 2048..2560) -> [b][256 h2][128 m][2]
        f16 (*t2)[136] = (f16(*)[136])smem;
        const f16* mpart = kvm + 2048;
        const int mb = pb - 64, b = mb >> 2, hc = mb & 3;
        #pragma unroll
        for (int k = 0; k < 8; ++k) {
            int idx = tid + 256 * k;
            int m = idx >> 4, hq = idx & 15;
            *(f16x8*)(&t2[m][hq * 8]) =
                *(const f16x8*)(mpart + (size_t)(b * 128 + m) * KVLD + hc * 128 + hq * 8);
        }
        __syncthreads();
        #pragma unroll
        for (int k = 0; k < 32; ++k) {
            int idx = tid + 256 * k;
            int h2l = idx >> 7, m = idx & 127;
            f16x2 v = { t2[m][h2l * 2], t2[m][h2l * 2 + 1] };
            *(f16x2*)(mpt + ((size_t)b * 256 + hc * 64 + h2l) * 256 + m * 2) = v;
        }
    }
}

// ---------------------------------------------------------------------------
// L4: fused relevance + scores + softmax + PV. grid 256 x 256 (8 s-rows/block).
// ---------------------------------------------------------------------------
__global__ __launch_bounds__(256) void relattn(
    const f16* __restrict__ qcat,    // [2048][QLD]: queries | q_part
    const f16* __restrict__ kvm,     // [256][KVLD]: keys in cols [0,1024)
    const f16* __restrict__ Vt,      // [1024][256]
    const f16* __restrict__ mpt,     // [b][256 h2][128 m][2]
    const float* __restrict__ W2,    // [512]
    const float* __restrict__ b2,    // [1]
    f16* __restrict__ attn_out,      // [2048][1024]
    float* __restrict__ attn_w)      // [2048][128]
{
    __shared__ __align__(16) char u[41984];      // qs|mps|w2s  then  sc
    __shared__ float rel_s[1024];                // [8][128] persistent
    __shared__ f16 Ps[8 * 136];

    const int tid = threadIdx.x;
    const int b = blockIdx.x >> 7, st = blockIdx.x & 127;
    const size_t rowbase = (size_t)b * SEQ + st * 8;
    const int w = tid >> 6, lane = tid & 63;
    const int l15 = lane & 15, l4 = lane >> 4;

    // ---------------- Phase R: relevance -> rel_s ----------------
    {
        f16* qs  = (f16*)u;                 // [8][512]  8 KB
        f16* mps = (f16*)(u + 8192);        // [64][256] 32 KB
        f16* w2s = (f16*)(u + 40960);       // [512]     1 KB

        {
            int r = tid >> 5, c = tid & 31;
            const f16* src = qcat + (rowbase + r) * QLD + 1024 + c * 16;
            *(f16x8*)(qs + r * 512 + c * 16)     = *(const f16x8*)(src);
            *(f16x8*)(qs + r * 512 + c * 16 + 8) = *(const f16x8*)(src + 8);
        }
        if (tid < 128) {
            float4 w4 = *(const float4*)(W2 + tid * 4);
            f16x4 hv = { (f16)w4.x, (f16)w4.y, (f16)w4.z, (f16)w4.w };
            *(f16x4*)(w2s + tid * 4) = hv;
        }
        const float b2v = b2[0];
        const int sg = w;

        float acc00 = 0.f, acc01 = 0.f, acc10 = 0.f, acc11 = 0.f;
        const f16* mptb = mpt + (size_t)b * 65536;

        for (int hc = 0; hc < 4; ++hc) {
            __syncthreads();
            {
                const f16x8* src = (const f16x8*)(mptb + hc * 16384);
                f16x8* dst = (f16x8*)mps;
                #pragma unroll
                for (int k = 0; k < 8; ++k) dst[tid + 256 * k] = src[tid + 256 * k];
            }
            __syncthreads();

            #pragma unroll 4
            for (int step = 0; step < 16; ++step) {
                const int habs = hc * 128 + step * 8;
                uint4 q0u = *(const uint4*)(qs + (2 * sg) * 512 + habs);
                uint4 q1u = *(const uint4*)(qs + (2 * sg + 1) * 512 + habs);
                uint4 wu  = *(const uint4*)(w2s + habs);
                const unsigned* q0p = (const unsigned*)&q0u;
                const unsigned* q1p = (const unsigned*)&q1u;
                const unsigned* wp_ = (const unsigned*)&wu;
                #pragma unroll
                for (int jj = 0; jj < 4; ++jj) {
                    uint2 mpu = *(const uint2*)(mps + ((step * 4 + jj) * 128 + 2 * lane) * 2);
                    f16x2 m0 = __builtin_bit_cast(f16x2, mpu.x);
                    f16x2 m1 = __builtin_bit_cast(f16x2, mpu.y);
                    f16x2 wp = __builtin_bit_cast(f16x2, wp_[jj]);
                    f16x2 q0 = __builtin_bit_cast(f16x2, q0p[jj]);
                    f16x2 q1 = __builtin_bit_cast(f16x2, q1p[jj]);
                    acc00 = dot2acc(relu2(q0 + m0), wp, acc00);
                    acc01 = dot2acc(relu2(q0 + m1), wp, acc01);
                    acc10 = dot2acc(relu2(q1 + m0), wp, acc10);
                    acc11 = dot2acc(relu2(q1 + m1), wp, acc11);
                }
            }
        }

        rel_s[(2 * sg) * 128 + 2 * lane]         = 1.f / (1.f + __expf(-(acc00 + b2v)));
        rel_s[(2 * sg) * 128 + 2 * lane + 1]     = 1.f / (1.f + __expf(-(acc01 + b2v)));
        rel_s[(2 * sg + 1) * 128 + 2 * lane]     = 1.f / (1.f + __expf(-(acc10 + b2v)));
        rel_s[(2 * sg + 1) * 128 + 2 * lane + 1] = 1.f / (1.f + __expf(-(acc11 + b2v)));
    }
    __syncthreads();   // rel_s ready; qs/mps dead -> sc may overwrite

    float* sc = (float*)u;   // [4][16][128] 32 KB

    // ---------------- Phase S: QK^T partials over k-quarter ----------------
    {
        f32x4 aq[8];
        #pragma unroll
        for (int n = 0; n < 8; ++n) aq[n] = (f32x4){0.f, 0.f, 0.f, 0.f};
        #pragma unroll
        for (int k4 = 0; k4 < 8; ++k4) {
            const int k0 = w * 256 + k4 * 32 + l4 * 8;
            f16x8 af = *(const f16x8*)(qcat + (rowbase + (l15 & 7)) * QLD + k0);
            #pragma unroll
            for (int n = 0; n < 8; ++n) {
                f16x8 bf = *(const f16x8*)(kvm + (size_t)(b * 128 + n * 16 + l15) * KVLD + k0);
                aq[n] = __builtin_amdgcn_mfma_f32_16x16x32_f16(af, bf, aq[n], 0, 0, 0);
            }
        }
        #pragma unroll
        for (int n = 0; n < 8; ++n)
            #pragma unroll
            for (int j = 0; j < 4; ++j)
                sc[(w * 16 + l4 * 4 + j) * 128 + n * 16 + l15] = aq[n][j];
    }
    __syncthreads();

    // ---------------- reduce partials, *rel/32, softmax ----------------
    {
        const int r = tid >> 5, seg = tid & 31;      // 8 rows x 32 segs x 4 m
        float4 xs = {0.f, 0.f, 0.f, 0.f};
        #pragma unroll
        for (int ww = 0; ww < 4; ++ww) {
            float4 p = *(const float4*)(sc + (ww * 16 + r) * 128 + seg * 4);
            xs.x += p.x; xs.y += p.y; xs.z += p.z; xs.w += p.w;
        }
        float4 rl = *(const float4*)(rel_s + r * 128 + seg * 4);
        float x[4];
        x[0] = xs.x * 0.03125f * rl.x; x[1] = xs.y * 0.03125f * rl.y;
        x[2] = xs.z * 0.03125f * rl.z; x[3] = xs.w * 0.03125f * rl.w;
        float mx = fmaxf(fmaxf(x[0], x[1]), fmaxf(x[2], x[3]));
        #pragma unroll
        for (int d = 1; d < 32; d <<= 1) mx = fmaxf(mx, __shfl_xor(mx, d));
        float ss = 0.f;
        #pragma unroll
        for (int c = 0; c < 4; ++c) { x[c] = __expf(x[c] - mx); ss += x[c]; }
        #pragma unroll
        for (int d = 1; d < 32; d <<= 1) ss += __shfl_xor(ss, d);
        const float inv = 1.f / ss;
        #pragma unroll
        for (int c = 0; c < 4; ++c) x[c] *= inv;
        float4 o = { x[0], x[1], x[2], x[3] };
        *(float4*)(attn_w + (rowbase + r) * 128 + seg * 4) = o;
        f16x4 ph = { (f16)x[0], (f16)x[1], (f16)x[2], (f16)x[3] };
        *(f16x4*)(Ps + r * 136 + seg * 4) = ph;
    }
    __syncthreads();

    // ---------------- Phase P: PV over d-quarter ----------------
    {
        f16x8 pa[4];
        #pragma unroll
        for (int k = 0; k < 4; ++k)
            pa[k] = *(const f16x8*)(Ps + (l15 & 7) * 136 + k * 32 + l4 * 8);
        #pragma unroll
        for (int n2 = 0; n2 < 16; ++n2) {
            f32x4 ac = (f32x4){0.f, 0.f, 0.f, 0.f};
            const int d0 = w * 256 + n2 * 16;
            #pragma unroll
            for (int k = 0; k < 4; ++k) {
                f16x8 bf = *(const f16x8*)(Vt + (size_t)(d0 + l15) * 256 + b * 128 + k * 32 + l4 * 8);
                ac = __builtin_amdgcn_mfma_f32_16x16x32_f16(pa[k], bf, ac, 0, 0, 0);
            }
            if (l4 < 2) {    // rows l4*4+j in [0,8)
                #pragma unroll
                for (int j = 0; j < 4; ++j)
                    attn_out[(rowbase + l4 * 4 + j) * 1024 + d0 + l15] = (f16)ac[j];
            }
        }
    }
}

// ---------------------------------------------------------------------------
// L5: out = attn_out @ Wo + bo. BN=64 for 512 blocks (2/CU). grid (16,32).
// ---------------------------------------------------------------------------
__global__ __launch_bounds__(256) void outgemm(
    const f16* __restrict__ attn_out, const f16* __restrict__ Wo_t,
    const float* __restrict__ bo, float* __restrict__ out)
{
    __shared__ __align__(16) char smem[32768];
    gemm_core<64>(attn_out, Wo_t, bo, out, nullptr, DM, DM, DM,
                  blockIdx.x, blockIdx.y, (f16*)smem, (f16*)(smem + 16384));
}

// ---------------------------------------------------------------------------
extern "C" void kernel_launch(void* const* d_in, const int* in_sizes, int n_in,
                              void* d_out, int out_size, void* d_ws, size_t ws_size,
                              hipStream_t stream)
{
    const float* hs  = (const float*)d_in[0];
    const float* mem = (const float*)d_in[1];
    const float* Wq  = (const float*)d_in[2];
    const float* bq  = (const float*)d_in[3];
    const float* Wk  = (const float*)d_in[4];
    const float* bk  = (const float*)d_in[5];
    const float* Wv  = (const float*)d_in[6];
    const float* bv  = (const float*)d_in[7];
    const float* Wo  = (const float*)d_in[8];
    const float* bo  = (const float*)d_in[9];
    const float* W1  = (const float*)d_in[10];  // (1536,512)
    const float* b1  = (const float*)d_in[11];
    const float* W2  = (const float*)d_in[12];
    const float* b2  = (const float*)d_in[13];

    float* out   = (float*)d_out;                       // (2,1024,1024)
    float* attnw = out + (size_t)BATCH * SEQ * DM;      // (2,1024,128)

    // workspace layout (16B-aligned, ~23 MB)
    char* wp = (char*)d_ws;
    f16* hsA     = (f16*)wp;  wp += (size_t)BATCH * SEQ * DM * 2;     // 4 MB (hs_f16 -> attn_out)
    f16* mem_f16 = (f16*)wp;  wp += (size_t)BATCH * MMEM * MEMD * 2;  // 0.25 MB
    f16* Wq_f16  = (f16*)wp;  wp += (size_t)DM * DM * 2;              // 2 MB
    f16* btbig   = (f16*)wp;  wp += (size_t)QLD * DM * 2;             // 3 MB
    f16* btcomb  = (f16*)wp;  wp += (size_t)KVLD * MEMD * 2;          // 2.5 MB
    f16* Wo_t    = (f16*)wp;  wp += (size_t)DM * DM * 2;              // 2 MB
    f16* W1q_t   = (f16*)wp;  wp += (size_t)RELH * DM * 2;            // 1 MB
    f16* qcat    = (f16*)wp;  wp += (size_t)BATCH * SEQ * QLD * 2;    // 6 MB
    f16* kvm     = (f16*)wp;  wp += (size_t)BATCH * MMEM * KVLD * 2;  // 1.25 MB
    f16* Vt      = (f16*)wp;  wp += (size_t)DM * BATCH * MMEM * 2;    // 0.5 MB
    f16* mpt     = (f16*)wp;  wp += (size_t)BATCH * MMEM * RELH * 2;  // 0.25 MB
    float* bcomb = (float*)wp; wp += (size_t)KVLD * 4;
    float* bqcomb= (float*)wp; wp += (size_t)QLD * 4;

    f16* hs_f16   = hsA;     // consumed by L3, then buffer reused by L4
    f16* attn_out = hsA;

    dim3 blk(256);

    // L1: casts + transposes + biases
    prep<<<dim3(2561), blk, 0, stream>>>(
        hs, mem, Wq, Wk, Wv, Wo, W1, bq, bk, bv, b1,
        hs_f16, mem_f16, Wq_f16, btbig, btcomb, Wo_t, W1q_t, bcomb, bqcomb);

    // L2: kvm GEMM + weight-combine + bias-combine
    smallgemms<<<dim3(145), blk, 0, stream>>>(
        mem_f16, btcomb, bcomb, kvm,
        W1q_t, Wq_f16, btbig + (size_t)1024 * DM, bq, bqcomb);

    // L3: [queries|q_part] GEMM + posttrans (Vt, mpt)
    biggemm<<<dim3(456), blk, 0, stream>>>(
        hs_f16, btbig, bqcomb, qcat, kvm, Vt, mpt);

    // L4: fused relevance + attention
    relattn<<<dim3(256), blk, 0, stream>>>(
        qcat, kvm, Vt, mpt, W2, b2, attn_out, attnw);

    // L5: out = attn_out @ Wo + bo
    outgemm<<<dim3(16, 32), blk, 0, stream>>>(attn_out, Wo_t, bo, out);
}